// Round 4
// baseline (676.057 us; speedup 1.0000x reference)
//
#include <hip/hip_runtime.h>
#include <hip/hip_cooperative_groups.h>
#include <math.h>

namespace cg = cooperative_groups;

// Problem constants
#define Bsz 64
#define Nn 512
#define Ff 128
#define Hh 256
#define OUTD 6

typedef __bf16 bf16x8 __attribute__((ext_vector_type(8)));
typedef float f32x4 __attribute__((ext_vector_type(4)));
typedef unsigned short ushort4v __attribute__((ext_vector_type(4)));

__device__ __forceinline__ unsigned short f2bf(float f) {
    unsigned u = __float_as_uint(f);
    u += 0x7FFFu + ((u >> 16) & 1u);        // RNE
    return (unsigned short)(u >> 16);
}
__device__ __forceinline__ float bf2f(unsigned short s) {
    return __uint_as_float(((unsigned)s) << 16);
}

// XOR swizzle of the 16B k-chunk within a 64B LDS row (kills ds_read_b128 bank conflicts)
#define SWZ(r) (((r) ^ ((r) >> 2)) & 3)

// async 16B global->LDS (DMA; LDS dest = wave-uniform base + lane*16)
__device__ __forceinline__ void async_ld16(const unsigned short* g, unsigned short* l) {
    __builtin_amdgcn_global_load_lds(
        (const __attribute__((address_space(1))) void*)g,
        (__attribute__((address_space(3))) void*)l,
        16, 0, 0);
}

#define LDH 40           // padded LDS row stride (bf16) for the h0 phase
#define AGP 136          // l0 aggL row stride (128 + 8 pad)
#define AGP1 264         // l1 aggL row stride (256 + 8 pad)

// ---------------- ONE cooperative mega-kernel: 5 phases, 4 grid syncs ----------
// 256 blocks x 512 threads = 1 block/CU (116.7 KB LDS). graph = blk & 63 in every
// phase -> all of graph b's producers/consumers stay on XCD b%8 => A and h tiles
// are L2-resident across phases. grid.sync() + device fences order the phases.
__global__ __launch_bounds__(512) void mega(
    const float* __restrict__ x, const float* __restrict__ sigma,
    const float* __restrict__ Wg, const float* __restrict__ bg,
    const float* __restrict__ Wrel0, const float* __restrict__ Wroot0,
    const float* __restrict__ brel0,
    const float* __restrict__ Wrel1, const float* __restrict__ Wroot1,
    const float* __restrict__ brel1,
    const float* __restrict__ Wrel2, const float* __restrict__ Wroot2,
    const float* __restrict__ brel2,
    const float* __restrict__ W1, const float* __restrict__ b1,
    const float* __restrict__ Wout, const float* __restrict__ bout,
    float* __restrict__ out, char* __restrict__ ws)
{
    // Workspace layout (bytes) — same as the multi-kernel version
    unsigned short* h0b  = (unsigned short*)(ws + 16777216);
    unsigned short* h0T  = (unsigned short*)(ws + 25165824);
    float*          sq   = (float*)(ws + 33554432);
    unsigned short* Aadj = (unsigned short*)(ws + 33685504);
    unsigned short* h1b  = (unsigned short*)(ws + 84017152);
    unsigned short* h1T  = (unsigned short*)(ws + 100794368);
    unsigned short* T0   = (unsigned short*)(ws + 167903232);   // WrelT0
    unsigned short* T1   = (unsigned short*)(ws + 167968768);   // WrootT0
    unsigned short* T2   = (unsigned short*)(ws + 168034304);   // WrelT1
    unsigned short* T3   = (unsigned short*)(ws + 168165376);   // WrootT1
    float*          w     = (float*)(ws + 168558592);
    float*          vpart = (float*)(ws + 168689664);
    float*          mpart = (float*)(ws + 169213952);

    cg::grid_group grid = cg::this_grid();

    __shared__ __align__(16) unsigned char SMEM[116736];

    int blk = blockIdx.x;
    int tid = threadIdx.x;
    int lane = tid & 63;
    int wave = tid >> 6;
    int quad = lane >> 4, l16 = lane & 15;
    int sr = lane >> 2, sc = lane & 3;
    int b = blk & 63;                 // graph — constant across ALL phases

    // ================= P0a: weight convert/transpose + w zero =================
    {
        int gid = blk * 512 + tid;
        #pragma unroll
        for (int it = 0; it < 2; ++it) {
            int idx = gid + it * 131072;
            if (idx < 196608) {
                const float* src; unsigned short* dst; int kin; int e;
                if      (idx <  32768) { src = Wrel0;  dst = T0; kin = 128; e = idx; }
                else if (idx <  65536) { src = Wroot0; dst = T1; kin = 128; e = idx - 32768; }
                else if (idx < 131072) { src = Wrel1;  dst = T2; kin = 256; e = idx - 65536; }
                else                   { src = Wroot1; dst = T3; kin = 256; e = idx - 131072; }
                int o = (kin == 128) ? (e >> 7) : (e >> 8);
                int i = e & (kin - 1);
                dst[e] = f2bf(src[(long)i * 256 + o]);
            } else if (idx < 229376) {
                w[idx - 196608] = 0.f;
            }
        }
    }

    // ================= P0b: h0 = x@Wg + bg (one 128-row tile / block) ==========
    {
        unsigned short* As = (unsigned short*)SMEM;           // 128*40 shorts
        unsigned short* Bs = As + 128 * LDH;
        float* rsq = (float*)(SMEM + 20480);
        int m0 = blk * 128;
        int wm = (wave >> 1) * 32, wn = (wave & 1) * 64;
        f32x4 acc[2][4] = {};

        for (int k0 = 0; k0 < Ff; k0 += 32) {
            __syncthreads();
            {
                int r = tid >> 2, ch = tid & 3;   // 512 threads = 128 rows x 4 chunks
                const float* px = x + (long)(m0 + r) * Ff + k0 + ch * 8;
                float4 xa = *(const float4*)px;
                float4 xb = *(const float4*)(px + 4);
                ushort4v pa, pb;
                pa[0] = f2bf(xa.x); pa[1] = f2bf(xa.y); pa[2] = f2bf(xa.z); pa[3] = f2bf(xa.w);
                pb[0] = f2bf(xb.x); pb[1] = f2bf(xb.y); pb[2] = f2bf(xb.z); pb[3] = f2bf(xb.w);
                *(ushort4v*)&As[r * LDH + ch * 8] = pa;
                *(ushort4v*)&As[r * LDH + ch * 8 + 4] = pb;
                int kk = k0 + ch * 8;
                ushort4v qa, qb;
                #pragma unroll
                for (int u = 0; u < 4; ++u) qa[u] = f2bf(Wg[(long)(kk + u) * 128 + r]);
                #pragma unroll
                for (int u = 0; u < 4; ++u) qb[u] = f2bf(Wg[(long)(kk + 4 + u) * 128 + r]);
                *(ushort4v*)&Bs[r * LDH + ch * 8] = qa;
                *(ushort4v*)&Bs[r * LDH + ch * 8 + 4] = qb;
            }
            __syncthreads();
            bf16x8 af[2], bfr[4];
            #pragma unroll
            for (int i = 0; i < 2; ++i)
                af[i] = *(const bf16x8*)&As[(wm + i * 16 + l16) * LDH + quad * 8];
            #pragma unroll
            for (int j = 0; j < 4; ++j)
                bfr[j] = *(const bf16x8*)&Bs[(wn + j * 16 + l16) * LDH + quad * 8];
            #pragma unroll
            for (int i = 0; i < 2; ++i)
                #pragma unroll
                for (int j = 0; j < 4; ++j)
                    acc[i][j] = __builtin_amdgcn_mfma_f32_16x16x32_bf16(
                        af[i], bfr[j], acc[i][j], 0, 0, 0);
        }

        if (tid < 128) rsq[tid] = 0.f;
        __syncthreads();

        #pragma unroll
        for (int i = 0; i < 2; ++i) {
            int lrow = wm + i * 16 + quad * 4;
            int mb = m0 + lrow;
            float rp0 = 0.f, rp1 = 0.f, rp2 = 0.f, rp3 = 0.f;
            #pragma unroll
            for (int j = 0; j < 4; ++j) {
                int n = wn + j * 16 + l16;
                f32x4 v = acc[i][j];
                float bv = bg[n];
                unsigned short s0 = f2bf(v[0] + bv), s1 = f2bf(v[1] + bv);
                unsigned short s2 = f2bf(v[2] + bv), s3 = f2bf(v[3] + bv);
                h0b[(long)(mb + 0) * Ff + n] = s0;
                h0b[(long)(mb + 1) * Ff + n] = s1;
                h0b[(long)(mb + 2) * Ff + n] = s2;
                h0b[(long)(mb + 3) * Ff + n] = s3;
                ushort4v p; p[0] = s0; p[1] = s1; p[2] = s2; p[3] = s3;
                long ti = ((long)(mb >> 9) * Ff + n) * 512 + (mb & 511);
                *(ushort4v*)&h0T[ti] = p;
                float f0 = bf2f(s0), f1 = bf2f(s1), f2 = bf2f(s2), f3 = bf2f(s3);
                rp0 += f0 * f0; rp1 += f1 * f1; rp2 += f2 * f2; rp3 += f3 * f3;
            }
            #pragma unroll
            for (int m = 1; m < 16; m <<= 1) {
                rp0 += __shfl_xor(rp0, m);
                rp1 += __shfl_xor(rp1, m);
                rp2 += __shfl_xor(rp2, m);
                rp3 += __shfl_xor(rp3, m);
            }
            if (l16 == 0) {
                atomicAdd(&rsq[lrow + 0], rp0);
                atomicAdd(&rsq[lrow + 1], rp1);
                atomicAdd(&rsq[lrow + 2], rp2);
                atomicAdd(&rsq[lrow + 3], rp3);
            }
        }
        __syncthreads();
        if (tid < 128) sq[m0 + tid] = rsq[tid];
    }
    __threadfence();
    grid.sync();
    __threadfence();

    // ================= P1: Gram -> A (4 quadrant-tiles / block) ================
    {
        unsigned short* Is = (unsigned short*)SMEM;        // 2*4096 shorts
        unsigned short* Js = Is + 8192;                    // 2*4096 shorts
        float* rsum = (float*)(SMEM + 32768);
        const unsigned short* H = h0b + (long)b * Nn * Ff;
        const float* SQ = sq + (long)b * Nn;
        unsigned short* Ab = Aadj + (long)b * Nn * Nn;
        float s = sigma[0];
        float inv2s2 = 1.0f / (2.0f * s * s);
        int wm = (wave >> 1) * 32, wn = (wave & 1) * 64;

        for (int t2 = 0; t2 < 4; ++t2) {
            int t = (blk >> 6) + t2 * 4;          // quadrant-tile 0..15
            int i0 = (t & 3) * 128, j0 = (t >> 2) * 128;
            __syncthreads();                       // prev tile fully consumed

            f32x4 acc[2][4] = {};
            auto issue = [&](int g) {
                int kk = g << 5;
                unsigned short* Id = Is + (g & 1) * 4096;
                unsigned short* Jd = Js + (g & 1) * 4096;
                int r = wave * 16 + sr;
                int c = sc ^ SWZ(r);
                async_ld16(H + (long)(i0 + r) * Ff + kk + c * 8, Id + (wave * 16) * 32);
                async_ld16(H + (long)(j0 + r) * Ff + kk + c * 8, Jd + (wave * 16) * 32);
            };
            issue(0);
            for (int g = 0; g < 4; ++g) {
                __syncthreads();
                if (g + 1 < 4) issue(g + 1);
                const unsigned short* Ib = Is + (g & 1) * 4096;
                const unsigned short* Jb = Js + (g & 1) * 4096;
                bf16x8 af[2], bfr[4];
                #pragma unroll
                for (int i = 0; i < 2; ++i) {
                    int r = wm + i * 16 + l16;
                    af[i] = *(const bf16x8*)&Ib[r * 32 + (quad ^ SWZ(r)) * 8];
                }
                #pragma unroll
                for (int j = 0; j < 4; ++j) {
                    int r = wn + j * 16 + l16;
                    bfr[j] = *(const bf16x8*)&Jb[r * 32 + (quad ^ SWZ(r)) * 8];
                }
                #pragma unroll
                for (int i = 0; i < 2; ++i)
                    #pragma unroll
                    for (int j = 0; j < 4; ++j)
                        acc[i][j] = __builtin_amdgcn_mfma_f32_16x16x32_bf16(
                            af[i], bfr[j], acc[i][j], 0, 0, 0);
            }

            if (tid < 128) rsum[tid] = 0.f;
            __syncthreads();

            #pragma unroll
            for (int i = 0; i < 2; ++i) {
                int lrow = wm + i * 16 + quad * 4;
                int rb = i0 + lrow;
                float rs0 = 0.f, rs1 = 0.f, rs2 = 0.f, rs3 = 0.f;
                #pragma unroll
                for (int j = 0; j < 4; ++j) {
                    int c = j0 + wn + j * 16 + l16;
                    float sqc = SQ[c];
                    f32x4 v = acc[i][j];
                    ushort4v pk;
                    float av[4];
                    #pragma unroll
                    for (int r4 = 0; r4 < 4; ++r4) {
                        int r = rb + r4;
                        float d = fmaxf(SQ[r] + sqc - 2.0f * v[r4], 0.0f);
                        unsigned short a = (r == c) ? (unsigned short)0
                                                    : f2bf(__expf(-d * inv2s2));
                        pk[r4] = a;
                        av[r4] = bf2f(a);
                    }
                    *(ushort4v*)&Ab[(long)c * Nn + rb] = pk;
                    rs0 += av[0]; rs1 += av[1]; rs2 += av[2]; rs3 += av[3];
                }
                #pragma unroll
                for (int m = 1; m < 16; m <<= 1) {
                    rs0 += __shfl_xor(rs0, m);
                    rs1 += __shfl_xor(rs1, m);
                    rs2 += __shfl_xor(rs2, m);
                    rs3 += __shfl_xor(rs3, m);
                }
                if (l16 == 0) {
                    atomicAdd(&rsum[lrow + 0], rs0);
                    atomicAdd(&rsum[lrow + 1], rs1);
                    atomicAdd(&rsum[lrow + 2], rs2);
                    atomicAdd(&rsum[lrow + 3], rs3);
                }
            }
            __syncthreads();
            if (tid < 128) atomicAdd(&w[(long)b * Nn + i0 + tid], rsum[tid]);
        }
    }
    __threadfence();
    grid.sync();
    __threadfence();

    // ================= P2: layer 0 (one 128-node tile / block) =================
    {
        unsigned short* SA = (unsigned short*)SMEM;   // 2 x 8192 shorts
        unsigned short* SB = SA + 16384;              // 2 x 4096 shorts
        unsigned short* aggL = SB + 8192;             // 128 x 136 shorts
        int nt = blk >> 6;                            // node tile 0..3
        int n0g = nt * 128;
        long nodeBase = (long)b * Nn + n0g;
        const unsigned short* HT = h0T + (long)b * Ff * Nn;
        const unsigned short* AR = Aadj + (long)b * Nn * Nn;

        // ---- stage 1: agg = A@h0 (M=128 feats, N=128 nodes, K=512) ----
        {
            int wm = (wave >> 1) * 32, wn = (wave & 1) * 64;
            f32x4 acc[2][4] = {};
            auto issue = [&](int g) {
                int kk = g << 5;
                unsigned short* Ad = SA + (g & 1) * 8192;
                unsigned short* Bd = SB + (g & 1) * 4096;
                int r = wave * 16 + sr;
                int c = sc ^ SWZ(r);
                async_ld16(HT + (long)r * Nn + kk + c * 8, Ad + (wave * 16) * 32);
                async_ld16(AR + (long)(n0g + r) * Nn + kk + c * 8, Bd + (wave * 16) * 32);
            };
            issue(0);
            for (int g = 0; g < 16; ++g) {
                __syncthreads();
                if (g + 1 < 16) issue(g + 1);
                const unsigned short* Ab = SA + (g & 1) * 8192;
                const unsigned short* Bb = SB + (g & 1) * 4096;
                bf16x8 af[2], bfr[4];
                #pragma unroll
                for (int i = 0; i < 2; ++i) {
                    int r = wm + i * 16 + l16;
                    af[i] = *(const bf16x8*)&Ab[r * 32 + (quad ^ SWZ(r)) * 8];
                }
                #pragma unroll
                for (int j = 0; j < 4; ++j) {
                    int r = wn + j * 16 + l16;
                    bfr[j] = *(const bf16x8*)&Bb[r * 32 + (quad ^ SWZ(r)) * 8];
                }
                #pragma unroll
                for (int i = 0; i < 2; ++i)
                    #pragma unroll
                    for (int j = 0; j < 4; ++j)
                        acc[i][j] = __builtin_amdgcn_mfma_f32_16x16x32_bf16(
                            af[i], bfr[j], acc[i][j], 0, 0, 0);
            }
            #pragma unroll
            for (int i = 0; i < 2; ++i) {
                int f = wm + i * 16 + quad * 4;
                #pragma unroll
                for (int j = 0; j < 4; ++j) {
                    int nl = wn + j * 16 + l16;
                    f32x4 v = acc[i][j];
                    ushort4v p;
                    p[0] = f2bf(v[0]); p[1] = f2bf(v[1]);
                    p[2] = f2bf(v[2]); p[3] = f2bf(v[3]);
                    *(ushort4v*)&aggL[nl * AGP + f] = p;
                }
            }
        }
        __syncthreads();

        // ---- stage 2: dense M=256 x N=128, wave tile 64x64 ----
        {
            int wm = (wave >> 1) * 64, wn = (wave & 1) * 64;
            f32x4 acc[4][4] = {};
            auto issue2 = [&](int g) {
                const unsigned short* Wp = (g < 4) ? T0 : T1;
                int kk = (g & 3) << 5;
                unsigned short* Ad = SA + (g & 1) * 8192;
                int r = wave * 16 + sr;
                int c = sc ^ SWZ(r);
                async_ld16(Wp + (long)r * Ff + kk + c * 8, Ad + (wave * 16) * 32);
                int r2 = 128 + r;
                int c2 = sc ^ SWZ(r2);
                async_ld16(Wp + (long)r2 * Ff + kk + c2 * 8, Ad + (128 + wave * 16) * 32);
                if (g >= 4) {
                    unsigned short* Bd = SB + (g & 1) * 4096;
                    async_ld16(h0b + (nodeBase + r) * Ff + kk + c * 8,
                               Bd + (wave * 16) * 32);
                }
            };
            issue2(0);
            for (int g = 0; g < 8; ++g) {
                __syncthreads();
                if (g + 1 < 8) issue2(g + 1);
                const unsigned short* Ab = SA + (g & 1) * 8192;
                bf16x8 af[4], bfr[4];
                #pragma unroll
                for (int i = 0; i < 4; ++i) {
                    int r = wm + i * 16 + l16;
                    af[i] = *(const bf16x8*)&Ab[r * 32 + (quad ^ SWZ(r)) * 8];
                }
                if (g < 4) {
                    #pragma unroll
                    for (int j = 0; j < 4; ++j) {
                        int nl = wn + j * 16 + l16;
                        bfr[j] = *(const bf16x8*)&aggL[nl * AGP + (g << 5) + quad * 8];
                    }
                } else {
                    const unsigned short* Bb = SB + (g & 1) * 4096;
                    #pragma unroll
                    for (int j = 0; j < 4; ++j) {
                        int r = wn + j * 16 + l16;
                        bfr[j] = *(const bf16x8*)&Bb[r * 32 + (quad ^ SWZ(r)) * 8];
                    }
                }
                #pragma unroll
                for (int i = 0; i < 4; ++i)
                    #pragma unroll
                    for (int j = 0; j < 4; ++j)
                        acc[i][j] = __builtin_amdgcn_mfma_f32_16x16x32_bf16(
                            af[i], bfr[j], acc[i][j], 0, 0, 0);
            }
            #pragma unroll
            for (int i = 0; i < 4; ++i) {
                int of = wm + i * 16 + quad * 4;
                float b0 = brel0[of + 0], b1 = brel0[of + 1];
                float b2 = brel0[of + 2], b3 = brel0[of + 3];
                #pragma unroll
                for (int j = 0; j < 4; ++j) {
                    int nl = wn + j * 16 + l16;
                    f32x4 v = acc[i][j];
                    float o0 = fmaxf(v[0] + b0, 0.f), o1 = fmaxf(v[1] + b1, 0.f);
                    float o2 = fmaxf(v[2] + b2, 0.f), o3 = fmaxf(v[3] + b3, 0.f);
                    ushort4v p;
                    p[0] = f2bf(o0); p[1] = f2bf(o1); p[2] = f2bf(o2); p[3] = f2bf(o3);
                    *(ushort4v*)&h1b[(nodeBase + nl) * Hh + of] = p;
                    long base = ((long)b * Hh) * 512 + n0g + nl;
                    h1T[base + (long)(of + 0) * 512] = p[0];
                    h1T[base + (long)(of + 1) * 512] = p[1];
                    h1T[base + (long)(of + 2) * 512] = p[2];
                    h1T[base + (long)(of + 3) * 512] = p[3];
                }
            }
        }
    }
    __threadfence();
    grid.sync();
    __threadfence();

    // ================= P3: layer 1 + pooled collapse (one 128-node tile) =======
    {
        unsigned short* SA = (unsigned short*)SMEM;   // 2 x 8192 shorts
        unsigned short* SB = SA + 16384;              // 2 x 4096 shorts
        unsigned short* aggL = SB + 8192;             // 128 x 264 shorts
        int nt = blk >> 6;
        int n0g = nt * 128;
        long nodeBase = (long)b * Nn + n0g;
        const unsigned short* HT = h1T + (long)b * Hh * Nn;
        const unsigned short* AR = Aadj + (long)b * Nn * Nn;
        int wm = (wave >> 1) * 64;
        int wn = (wave & 1) * 64;

        // ---- stage 1: aggT (M=256 feats, N=128 nodes, K=512) ----
        {
            f32x4 acc[4][4] = {};
            auto issue = [&](int g) {
                int kk = g << 5;
                unsigned short* Ad = SA + (g & 1) * 8192;
                int r = wave * 16 + sr;
                int c = sc ^ SWZ(r);
                async_ld16(HT + (long)r * Nn + kk + c * 8, Ad + (wave * 16) * 32);
                int r2 = 128 + r;
                int c2 = sc ^ SWZ(r2);
                async_ld16(HT + (long)r2 * Nn + kk + c2 * 8, Ad + (128 + wave * 16) * 32);
                unsigned short* Bd = SB + (g & 1) * 4096;
                async_ld16(AR + (long)(n0g + r) * Nn + kk + c * 8, Bd + (wave * 16) * 32);
            };
            issue(0);
            for (int g = 0; g < 16; ++g) {
                __syncthreads();
                if (g + 1 < 16) issue(g + 1);
                const unsigned short* Ab = SA + (g & 1) * 8192;
                const unsigned short* Bb = SB + (g & 1) * 4096;
                bf16x8 af[4], bfr[4];
                #pragma unroll
                for (int i = 0; i < 4; ++i) {
                    int r = wm + i * 16 + l16;
                    af[i] = *(const bf16x8*)&Ab[r * 32 + (quad ^ SWZ(r)) * 8];
                }
                #pragma unroll
                for (int j = 0; j < 4; ++j) {
                    int r = wn + j * 16 + l16;
                    bfr[j] = *(const bf16x8*)&Bb[r * 32 + (quad ^ SWZ(r)) * 8];
                }
                #pragma unroll
                for (int i = 0; i < 4; ++i)
                    #pragma unroll
                    for (int j = 0; j < 4; ++j)
                        acc[i][j] = __builtin_amdgcn_mfma_f32_16x16x32_bf16(
                            af[i], bfr[j], acc[i][j], 0, 0, 0);
            }
            #pragma unroll
            for (int i = 0; i < 4; ++i) {
                int f = wm + i * 16 + quad * 4;
                #pragma unroll
                for (int j = 0; j < 4; ++j) {
                    int nl = wn + j * 16 + l16;
                    f32x4 v = acc[i][j];
                    ushort4v p;
                    p[0] = f2bf(v[0]); p[1] = f2bf(v[1]);
                    p[2] = f2bf(v[2]); p[3] = f2bf(v[3]);
                    *(ushort4v*)&aggL[nl * AGP1 + f] = p;
                }
            }
        }
        __syncthreads();

        // ---- stage 2: dense (M=256, N=128, K=256+256) ----
        f32x4 acc[4][4] = {};
        auto issue2 = [&](int g) {
            const unsigned short* Wp = (g < 8) ? T2 : T3;
            int kk = (g & 7) << 5;
            unsigned short* Ad = SA + (g & 1) * 8192;
            int r = wave * 16 + sr;
            int c = sc ^ SWZ(r);
            async_ld16(Wp + (long)r * Hh + kk + c * 8, Ad + (wave * 16) * 32);
            int r2 = 128 + r;
            int c2 = sc ^ SWZ(r2);
            async_ld16(Wp + (long)r2 * Hh + kk + c2 * 8, Ad + (128 + wave * 16) * 32);
            if (g >= 8) {
                unsigned short* Bd = SB + (g & 1) * 4096;
                async_ld16(h1b + (nodeBase + r) * Hh + kk + c * 8, Bd + (wave * 16) * 32);
            }
        };
        issue2(0);
        for (int g = 0; g < 16; ++g) {
            __syncthreads();
            if (g + 1 < 16) issue2(g + 1);
            const unsigned short* Ab = SA + (g & 1) * 8192;
            bf16x8 af[4], bfr[4];
            #pragma unroll
            for (int i = 0; i < 4; ++i) {
                int r = wm + i * 16 + l16;
                af[i] = *(const bf16x8*)&Ab[r * 32 + (quad ^ SWZ(r)) * 8];
            }
            if (g < 8) {
                #pragma unroll
                for (int j = 0; j < 4; ++j) {
                    int nl = wn + j * 16 + l16;
                    bfr[j] = *(const bf16x8*)&aggL[nl * AGP1 + (g << 5) + quad * 8];
                }
            } else {
                const unsigned short* Bb = SB + (g & 1) * 4096;
                #pragma unroll
                for (int j = 0; j < 4; ++j) {
                    int r = wn + j * 16 + l16;
                    bfr[j] = *(const bf16x8*)&Bb[r * 32 + (quad ^ SWZ(r)) * 8];
                }
            }
            #pragma unroll
            for (int i = 0; i < 4; ++i)
                #pragma unroll
                for (int j = 0; j < 4; ++j)
                    acc[i][j] = __builtin_amdgcn_mfma_f32_16x16x32_bf16(
                        af[i], bfr[j], acc[i][j], 0, 0, 0);
        }

        #pragma unroll
        for (int i = 0; i < 4; ++i) {
            int lf = wm + i * 16 + quad * 4;
            float b0 = brel1[lf + 0], b1 = brel1[lf + 1];
            float b2 = brel1[lf + 2], b3 = brel1[lf + 3];
            float vp0 = 0.f, vp1 = 0.f, vp2 = 0.f, vp3 = 0.f;
            float mp0 = 0.f, mp1 = 0.f, mp2 = 0.f, mp3 = 0.f;
            #pragma unroll
            for (int j = 0; j < 4; ++j) {
                long node = nodeBase + wn + j * 16 + l16;
                f32x4 v = acc[i][j];
                float o0 = fmaxf(v[0] + b0, 0.f), o1 = fmaxf(v[1] + b1, 0.f);
                float o2 = fmaxf(v[2] + b2, 0.f), o3 = fmaxf(v[3] + b3, 0.f);
                float h0v = bf2f(f2bf(o0)), h1v = bf2f(f2bf(o1));
                float h2v = bf2f(f2bf(o2)), h3v = bf2f(f2bf(o3));
                float wv = w[node];
                vp0 += wv * h0v; vp1 += wv * h1v; vp2 += wv * h2v; vp3 += wv * h3v;
                mp0 += h0v; mp1 += h1v; mp2 += h2v; mp3 += h3v;
            }
            #pragma unroll
            for (int m = 1; m < 16; m <<= 1) {
                vp0 += __shfl_xor(vp0, m); vp1 += __shfl_xor(vp1, m);
                vp2 += __shfl_xor(vp2, m); vp3 += __shfl_xor(vp3, m);
                mp0 += __shfl_xor(mp0, m); mp1 += __shfl_xor(mp1, m);
                mp2 += __shfl_xor(mp2, m); mp3 += __shfl_xor(mp3, m);
            }
            if (l16 == 0) {
                long o = ((long)(b * 8 + nt * 2 + (wave & 1))) * Hh + lf;
                float4 vv = {vp0, vp1, vp2, vp3};
                float4 mm = {mp0, mp1, mp2, mp3};
                *(float4*)&vpart[o] = vv;
                *(float4*)&mpart[o] = mm;
            }
        }
    }
    __threadfence();
    grid.sync();
    __threadfence();

    // ================= P4: head (blocks 0..63 only) ============================
    if (blk < 64) {
        float* vs = (float*)SMEM;
        float* ms = vs + Hh;
        float* gs = ms + Hh;
        float* g2 = gs + Hh;
        int j = tid;
        bool act = (tid < Hh);
        if (act) {
            float vp = 0.f, mp = 0.f;
            #pragma unroll
            for (int p = 0; p < 8; ++p) {
                long o = ((long)(blk * 8 + p)) * Hh + j;
                vp += vpart[o];
                mp += mpart[o];
            }
            vs[j] = vp * (1.0f / (float)Nn);
            ms[j] = mp * (1.0f / (float)Nn);
        }
        __syncthreads();
        if (act) {
            float s = brel2[j];
            for (int c = 0; c < Hh; ++c)
                s += vs[c] * Wrel2[c * Hh + j] + ms[c] * Wroot2[c * Hh + j];
            gs[j] = s;
        }
        __syncthreads();
        if (act) {
            float t = b1[j];
            for (int k = 0; k < Hh; ++k) t += gs[k] * W1[k * Hh + j];
            g2[j] = fmaxf(t, 0.f);
        }
        __syncthreads();
        if (act && j < OUTD) {
            float s2 = bout[j];
            for (int k = 0; k < Hh; ++k) s2 += g2[k] * Wout[k * OUTD + j];
            out[blk * OUTD + j] = s2;
        }
    }
}

extern "C" void kernel_launch(void* const* d_in, const int* in_sizes, int n_in,
                              void* d_out, int out_size, void* d_ws, size_t ws_size,
                              hipStream_t stream) {
    const float* x      = (const float*)d_in[0];
    const float* sigma  = (const float*)d_in[4];
    const float* Wg     = (const float*)d_in[5];
    const float* bg     = (const float*)d_in[6];
    const float* Wrel0  = (const float*)d_in[7];
    const float* Wroot0 = (const float*)d_in[8];
    const float* brel0  = (const float*)d_in[9];
    const float* Wrel1  = (const float*)d_in[10];
    const float* Wroot1 = (const float*)d_in[11];
    const float* brel1  = (const float*)d_in[12];
    const float* Wrel2  = (const float*)d_in[13];
    const float* Wroot2 = (const float*)d_in[14];
    const float* brel2  = (const float*)d_in[15];
    const float* W1     = (const float*)d_in[16];
    const float* b1     = (const float*)d_in[17];
    const float* Wout   = (const float*)d_in[18];
    const float* bout   = (const float*)d_in[19];
    float* out = (float*)d_out;
    char* ws = (char*)d_ws;

    void* kargs[] = {
        (void*)&x, (void*)&sigma, (void*)&Wg, (void*)&bg,
        (void*)&Wrel0, (void*)&Wroot0, (void*)&brel0,
        (void*)&Wrel1, (void*)&Wroot1, (void*)&brel1,
        (void*)&Wrel2, (void*)&Wroot2, (void*)&brel2,
        (void*)&W1, (void*)&b1, (void*)&Wout, (void*)&bout,
        (void*)&out, (void*)&ws
    };
    hipLaunchCooperativeKernel((const void*)mega, dim3(256), dim3(512),
                               kargs, 0, stream);
}

// Round 5
// 208.530 us; speedup vs baseline: 3.2420x; 3.2420x over previous
//
#include <hip/hip_runtime.h>
#include <math.h>

// Problem constants
#define Bsz 64
#define Nn 512
#define Ff 128
#define Hh 256
#define OUTD 6
#define MTOT (Bsz * Nn)   // 32768

typedef __bf16 bf16x8 __attribute__((ext_vector_type(8)));
typedef float f32x4 __attribute__((ext_vector_type(4)));
typedef unsigned short ushort4v __attribute__((ext_vector_type(4)));

__device__ __forceinline__ unsigned short f2bf(float f) {
    unsigned u = __float_as_uint(f);
    u += 0x7FFFu + ((u >> 16) & 1u);        // RNE
    return (unsigned short)(u >> 16);
}
__device__ __forceinline__ float bf2f(unsigned short s) {
    return __uint_as_float(((unsigned)s) << 16);
}

// XOR swizzle of the 16B k-chunk within a 64B LDS row (kills ds_read_b128 bank conflicts)
#define SWZ(r) (((r) ^ ((r) >> 2)) & 3)

// async 16B global->LDS (DMA; LDS dest = wave-uniform base + lane*16)
__device__ __forceinline__ void async_ld16(const unsigned short* g, unsigned short* l) {
    __builtin_amdgcn_global_load_lds(
        (const __attribute__((address_space(1))) void*)g,
        (__attribute__((address_space(3))) void*)l,
        16, 0, 0);
}

// counted vmcnt wait
__device__ __forceinline__ void wait_vm(int n) {
    switch (n) {
        case 0: asm volatile("s_waitcnt vmcnt(0)" ::: "memory"); break;
        case 1: asm volatile("s_waitcnt vmcnt(1)" ::: "memory"); break;
        case 2: asm volatile("s_waitcnt vmcnt(2)" ::: "memory"); break;
        case 3: asm volatile("s_waitcnt vmcnt(3)" ::: "memory"); break;
        case 4: asm volatile("s_waitcnt vmcnt(4)" ::: "memory"); break;
        case 5: asm volatile("s_waitcnt vmcnt(5)" ::: "memory"); break;
        default: asm volatile("s_waitcnt vmcnt(6)" ::: "memory"); break;
    }
}
__device__ __forceinline__ void pipe_barrier(int n) {
    wait_vm(n);
    __builtin_amdgcn_s_barrier();
    __builtin_amdgcn_sched_barrier(0);
}

#define LDH 40           // padded LDS row stride (bf16) for the non-async h0 kernel
#define TSZ (128 * 32)   // one LDS tile: 128 rows x 32 bf16 (8 KB)
#define ATS (256 * 32)   // one LDS A-tile: 256 rows x 32 bf16 (16 KB)
#define AGP 136          // fused_l0 aggL row stride (128 + 8 pad)
#define AGP1 264         // fused_l1 aggL row stride (256 + 8 pad)
#define ATP 132          // gram Atile LDS row stride (128 + 4 pad, 8B-aligned rows)

// ---------------- FUSED layer 0: A@h (K=512) + dense (K=128+128) -----------------
__global__ __launch_bounds__(512) void fused_l0(
    const unsigned short* __restrict__ h0T,   // [graph][128][512]
    const unsigned short* __restrict__ Arows, // [graph][512][512]
    const unsigned short* __restrict__ h0b,   // [node][128]
    const unsigned short* __restrict__ WrelT0,  // [256][128]
    const unsigned short* __restrict__ WrootT0, // [256][128]
    const float* __restrict__ brel0,
    unsigned short* __restrict__ h1b,  // [node][256]
    unsigned short* __restrict__ h1T)  // [graph][256][512]
{
    int id = blockIdx.x;
    int b = id & 63;               // graph (XCD locality)
    int nt = id >> 6;              // node tile 0..3
    int n0g = nt * 128;
    long nodeBase = (long)b * Nn + n0g;

    const unsigned short* HT = h0T + (long)b * Ff * Nn;
    const unsigned short* AR = Arows + (long)b * Nn * Nn;

    __shared__ unsigned short SA[3 * ATS];     // 48 KB
    __shared__ unsigned short SB[3 * TSZ];     // 24 KB
    __shared__ unsigned short aggL[128 * AGP]; // ~35 KB

    int tid = threadIdx.x;
    int lane = tid & 63;
    int wave = tid >> 6;
    int quad = lane >> 4, l16 = lane & 15;
    int sr = lane >> 2, sc = lane & 3;

    // ---------- stage 1: agg tile = A@h0 (M=128 feats, N=128 nodes, K=512) ----------
    {
        int wm = (wave >> 1) * 32, wn = (wave & 1) * 64;
        f32x4 acc[2][4] = {};
        auto issue = [&](int g) {
            int kk = g << 5;
            unsigned short* Ad = SA + (g % 3) * ATS;
            unsigned short* Bd = SB + (g % 3) * TSZ;
            int r = wave * 16 + sr;
            int c = sc ^ SWZ(r);
            async_ld16(HT + (long)r * Nn + kk + c * 8, Ad + (wave * 16) * 32);
            async_ld16(AR + (long)(n0g + r) * Nn + kk + c * 8, Bd + (wave * 16) * 32);
        };
        issue(0); issue(1);
        for (int g = 0; g < 16; ++g) {
            pipe_barrier(g + 1 < 16 ? 2 : 0);
            if (g + 2 < 16) issue(g + 2);
            const unsigned short* Ab = SA + (g % 3) * ATS;
            const unsigned short* Bb = SB + (g % 3) * TSZ;
            bf16x8 af[2], bfr[4];
            #pragma unroll
            for (int i = 0; i < 2; ++i) {
                int r = wm + i * 16 + l16;
                af[i] = *(const bf16x8*)&Ab[r * 32 + (quad ^ SWZ(r)) * 8];
            }
            #pragma unroll
            for (int j = 0; j < 4; ++j) {
                int r = wn + j * 16 + l16;
                bfr[j] = *(const bf16x8*)&Bb[r * 32 + (quad ^ SWZ(r)) * 8];
            }
            #pragma unroll
            for (int i = 0; i < 2; ++i)
                #pragma unroll
                for (int j = 0; j < 4; ++j)
                    acc[i][j] = __builtin_amdgcn_mfma_f32_16x16x32_bf16(
                        af[i], bfr[j], acc[i][j], 0, 0, 0);
        }
        #pragma unroll
        for (int i = 0; i < 2; ++i) {
            int f = wm + i * 16 + quad * 4;
            #pragma unroll
            for (int j = 0; j < 4; ++j) {
                int nl = wn + j * 16 + l16;
                f32x4 v = acc[i][j];
                ushort4v p;
                p[0] = f2bf(v[0]); p[1] = f2bf(v[1]);
                p[2] = f2bf(v[2]); p[3] = f2bf(v[3]);
                *(ushort4v*)&aggL[nl * AGP + f] = p;
            }
        }
    }
    __syncthreads();

    // ---------- stage 2: dense, M=256 outfeats x N=128 nodes, wave tile 64x64 ----------
    {
        int wm = (wave >> 1) * 64, wn = (wave & 1) * 64;
        f32x4 acc[4][4] = {};
        auto issue2 = [&](int g) {
            const unsigned short* Wp = (g < 4) ? WrelT0 : WrootT0;
            int kk = (g & 3) << 5;
            unsigned short* Ad = SA + (g % 3) * ATS;
            int r = wave * 16 + sr;
            int c = sc ^ SWZ(r);
            async_ld16(Wp + (long)r * Ff + kk + c * 8, Ad + (wave * 16) * 32);
            int r2 = 128 + r;
            int c2 = sc ^ SWZ(r2);
            async_ld16(Wp + (long)r2 * Ff + kk + c2 * 8, Ad + (128 + wave * 16) * 32);
            if (g >= 4) {
                unsigned short* Bd = SB + (g % 3) * TSZ;
                async_ld16(h0b + (nodeBase + r) * Ff + kk + c * 8,
                           Bd + (wave * 16) * 32);
            }
        };
        issue2(0); issue2(1);
        for (int g = 0; g < 8; ++g) {
            int nx = g + 1;
            pipe_barrier(nx >= 8 ? 0 : (nx < 4 ? 2 : 3));
            if (g + 2 < 8) issue2(g + 2);
            const unsigned short* Ab = SA + (g % 3) * ATS;
            bf16x8 af[4], bfr[4];
            #pragma unroll
            for (int i = 0; i < 4; ++i) {
                int r = wm + i * 16 + l16;
                af[i] = *(const bf16x8*)&Ab[r * 32 + (quad ^ SWZ(r)) * 8];
            }
            if (g < 4) {
                #pragma unroll
                for (int j = 0; j < 4; ++j) {
                    int nl = wn + j * 16 + l16;
                    bfr[j] = *(const bf16x8*)&aggL[nl * AGP + (g << 5) + quad * 8];
                }
            } else {
                const unsigned short* Bb = SB + (g % 3) * TSZ;
                #pragma unroll
                for (int j = 0; j < 4; ++j) {
                    int r = wn + j * 16 + l16;
                    bfr[j] = *(const bf16x8*)&Bb[r * 32 + (quad ^ SWZ(r)) * 8];
                }
            }
            #pragma unroll
            for (int i = 0; i < 4; ++i)
                #pragma unroll
                for (int j = 0; j < 4; ++j)
                    acc[i][j] = __builtin_amdgcn_mfma_f32_16x16x32_bf16(
                        af[i], bfr[j], acc[i][j], 0, 0, 0);
        }
        #pragma unroll
        for (int i = 0; i < 4; ++i) {
            int of = wm + i * 16 + quad * 4;
            float b0 = brel0[of + 0], b1 = brel0[of + 1];
            float b2 = brel0[of + 2], b3 = brel0[of + 3];
            #pragma unroll
            for (int j = 0; j < 4; ++j) {
                int nl = wn + j * 16 + l16;
                f32x4 v = acc[i][j];
                float o0 = fmaxf(v[0] + b0, 0.f), o1 = fmaxf(v[1] + b1, 0.f);
                float o2 = fmaxf(v[2] + b2, 0.f), o3 = fmaxf(v[3] + b3, 0.f);
                ushort4v p;
                p[0] = f2bf(o0); p[1] = f2bf(o1); p[2] = f2bf(o2); p[3] = f2bf(o3);
                *(ushort4v*)&h1b[(nodeBase + nl) * Hh + of] = p;
                long base = ((long)b * Hh) * 512 + n0g + nl;
                h1T[base + (long)(of + 0) * 512] = p[0];
                h1T[base + (long)(of + 1) * 512] = p[1];
                h1T[base + (long)(of + 2) * 512] = p[2];
                h1T[base + (long)(of + 3) * 512] = p[3];
            }
        }
    }
}

// ---------------- FUSED layer 1 + layer-2-collapse pooling -----------------------
__global__ __launch_bounds__(512) void fused_l1(
    const unsigned short* __restrict__ h1T,   // [graph][256][512]
    const unsigned short* __restrict__ Arows, // [graph][512][512]
    const unsigned short* __restrict__ h1b,   // [node][256]
    const unsigned short* __restrict__ WrelT1,  // [256][256]
    const unsigned short* __restrict__ WrootT1, // [256][256]
    const float* __restrict__ brel1,
    const float* __restrict__ w,
    float* __restrict__ vpart, float* __restrict__ mpart)  // [512][256]
{
    constexpr int BTS = 128 * 32;   // B-op tile shorts (8 KB)

    int id = blockIdx.x;
    int b = id & 63;               // graph
    int nt = id >> 6;              // node tile 0..3
    int n0g = nt * 128;
    long nodeBase = (long)b * Nn + n0g;

    const unsigned short* HT = h1T + (long)b * Hh * Nn;
    const unsigned short* AR = Arows + (long)b * Nn * Nn;

    __shared__ unsigned short SA[3 * ATS];      // 48 KB
    __shared__ unsigned short SB[3 * BTS];      // 24 KB
    __shared__ unsigned short aggL[128 * AGP1]; // ~66 KB

    int tid = threadIdx.x;
    int lane = tid & 63;
    int wave = tid >> 6;
    int quad = lane >> 4, l16 = lane & 15;
    int wm = (wave >> 1) * 64;
    int wn = (wave & 1) * 64;
    int sr = lane >> 2, sc = lane & 3;

    // ---------- stage 1: aggT (M=256 feats, N=128 nodes, K=512) ----------
    {
        f32x4 acc[4][4] = {};
        auto issue = [&](int g) {
            int kk = g << 5;
            unsigned short* Ad = SA + (g % 3) * ATS;
            int r = wave * 16 + sr;
            int c = sc ^ SWZ(r);
            async_ld16(HT + (long)r * Nn + kk + c * 8, Ad + (wave * 16) * 32);
            int r2 = 128 + r;
            int c2 = sc ^ SWZ(r2);
            async_ld16(HT + (long)r2 * Nn + kk + c2 * 8, Ad + (128 + wave * 16) * 32);
            unsigned short* Bd = SB + (g % 3) * BTS;
            async_ld16(AR + (long)(n0g + r) * Nn + kk + c * 8, Bd + (wave * 16) * 32);
        };
        issue(0); issue(1);
        for (int g = 0; g < 16; ++g) {
            pipe_barrier(g + 1 < 16 ? 3 : 0);
            if (g + 2 < 16) issue(g + 2);
            const unsigned short* Ab = SA + (g % 3) * ATS;
            const unsigned short* Bb = SB + (g % 3) * BTS;
            bf16x8 af[4], bfr[4];
            #pragma unroll
            for (int i = 0; i < 4; ++i) {
                int r = wm + i * 16 + l16;
                af[i] = *(const bf16x8*)&Ab[r * 32 + (quad ^ SWZ(r)) * 8];
            }
            #pragma unroll
            for (int j = 0; j < 4; ++j) {
                int r = wn + j * 16 + l16;
                bfr[j] = *(const bf16x8*)&Bb[r * 32 + (quad ^ SWZ(r)) * 8];
            }
            #pragma unroll
            for (int i = 0; i < 4; ++i)
                #pragma unroll
                for (int j = 0; j < 4; ++j)
                    acc[i][j] = __builtin_amdgcn_mfma_f32_16x16x32_bf16(
                        af[i], bfr[j], acc[i][j], 0, 0, 0);
        }
        #pragma unroll
        for (int i = 0; i < 4; ++i) {
            int f = wm + i * 16 + quad * 4;
            #pragma unroll
            for (int j = 0; j < 4; ++j) {
                int nl = wn + j * 16 + l16;
                f32x4 v = acc[i][j];
                ushort4v p;
                p[0] = f2bf(v[0]); p[1] = f2bf(v[1]);
                p[2] = f2bf(v[2]); p[3] = f2bf(v[3]);
                *(ushort4v*)&aggL[nl * AGP1 + f] = p;
            }
        }
    }
    __syncthreads();

    // ---------- stage 2: dense (M=256 outfeats, N=128 nodes, K=256+256) ----------
    f32x4 acc[4][4] = {};
    auto issue2 = [&](int g) {
        const unsigned short* Wp = (g < 8) ? WrelT1 : WrootT1;
        int kk = (g & 7) << 5;
        unsigned short* Ad = SA + (g % 3) * ATS;
        int r = wave * 16 + sr;
        int c = sc ^ SWZ(r);
        async_ld16(Wp + (long)r * Hh + kk + c * 8, Ad + (wave * 16) * 32);
        int r2 = 128 + r;
        int c2 = sc ^ SWZ(r2);
        async_ld16(Wp + (long)r2 * Hh + kk + c2 * 8, Ad + (128 + wave * 16) * 32);
        if (g >= 8) {
            unsigned short* Bd = SB + (g % 3) * BTS;
            async_ld16(h1b + (nodeBase + r) * Hh + kk + c * 8, Bd + (wave * 16) * 32);
        }
    };
    issue2(0); issue2(1);
    for (int g = 0; g < 16; ++g) {
        int nx = g + 1;
        pipe_barrier(nx >= 16 ? 0 : (nx < 8 ? 2 : 3));
        if (g + 2 < 16) issue2(g + 2);
        const unsigned short* Ab = SA + (g % 3) * ATS;
        bf16x8 af[4], bfr[4];
        #pragma unroll
        for (int i = 0; i < 4; ++i) {
            int r = wm + i * 16 + l16;
            af[i] = *(const bf16x8*)&Ab[r * 32 + (quad ^ SWZ(r)) * 8];
        }
        if (g < 8) {
            #pragma unroll
            for (int j = 0; j < 4; ++j) {
                int nl = wn + j * 16 + l16;
                bfr[j] = *(const bf16x8*)&aggL[nl * AGP1 + (g << 5) + quad * 8];
            }
        } else {
            const unsigned short* Bb = SB + (g % 3) * BTS;
            #pragma unroll
            for (int j = 0; j < 4; ++j) {
                int r = wn + j * 16 + l16;
                bfr[j] = *(const bf16x8*)&Bb[r * 32 + (quad ^ SWZ(r)) * 8];
            }
        }
        #pragma unroll
        for (int i = 0; i < 4; ++i)
            #pragma unroll
            for (int j = 0; j < 4; ++j)
                acc[i][j] = __builtin_amdgcn_mfma_f32_16x16x32_bf16(
                    af[i], bfr[j], acc[i][j], 0, 0, 0);
    }

    #pragma unroll
    for (int i = 0; i < 4; ++i) {
        int lf = wm + i * 16 + quad * 4;
        float b0 = brel1[lf + 0], b1 = brel1[lf + 1];
        float b2 = brel1[lf + 2], b3 = brel1[lf + 3];
        float vp0 = 0.f, vp1 = 0.f, vp2 = 0.f, vp3 = 0.f;
        float mp0 = 0.f, mp1 = 0.f, mp2 = 0.f, mp3 = 0.f;
        #pragma unroll
        for (int j = 0; j < 4; ++j) {
            long node = nodeBase + wn + j * 16 + l16;
            f32x4 v = acc[i][j];
            float o0 = fmaxf(v[0] + b0, 0.f), o1 = fmaxf(v[1] + b1, 0.f);
            float o2 = fmaxf(v[2] + b2, 0.f), o3 = fmaxf(v[3] + b3, 0.f);
            float h0v = bf2f(f2bf(o0)), h1v = bf2f(f2bf(o1));
            float h2v = bf2f(f2bf(o2)), h3v = bf2f(f2bf(o3));
            float wv = w[node];
            vp0 += wv * h0v; vp1 += wv * h1v; vp2 += wv * h2v; vp3 += wv * h3v;
            mp0 += h0v; mp1 += h1v; mp2 += h2v; mp3 += h3v;
        }
        #pragma unroll
        for (int m = 1; m < 16; m <<= 1) {
            vp0 += __shfl_xor(vp0, m); vp1 += __shfl_xor(vp1, m);
            vp2 += __shfl_xor(vp2, m); vp3 += __shfl_xor(vp3, m);
            mp0 += __shfl_xor(mp0, m); mp1 += __shfl_xor(mp1, m);
            mp2 += __shfl_xor(mp2, m); mp3 += __shfl_xor(mp3, m);
        }
        if (l16 == 0) {
            long o = ((long)(b * 8 + nt * 2 + (wave & 1))) * Hh + lf;
            float4 vv = {vp0, vp1, vp2, vp3};
            float4 mm = {mp0, mp1, mp2, mp3};
            *(float4*)&vpart[o] = vv;
            *(float4*)&mpart[o] = mm;
        }
    }
}

// ---------------- prep: weight convert/transpose + w zero + h0 MFMA ------------
__global__ __launch_bounds__(256) void prep_h0(
    const float* __restrict__ x, const float* __restrict__ Wg,
    const float* __restrict__ bg,
    const float* __restrict__ Wrel0, const float* __restrict__ Wroot0,
    const float* __restrict__ Wrel1, const float* __restrict__ Wroot1,
    unsigned short* __restrict__ T0, unsigned short* __restrict__ T1,
    unsigned short* __restrict__ T2, unsigned short* __restrict__ T3,
    float* __restrict__ w,
    unsigned short* __restrict__ h0b, unsigned short* __restrict__ h0T,
    float* __restrict__ sqv)
{
    if (blockIdx.x < 896) {
        int idx = blockIdx.x * 256 + threadIdx.x;
        if (idx >= 196608) { w[idx - 196608] = 0.f; return; }
        const float* src; unsigned short* dst; int kin; int e;
        if      (idx <  32768) { src = Wrel0;  dst = T0; kin = 128; e = idx; }
        else if (idx <  65536) { src = Wroot0; dst = T1; kin = 128; e = idx - 32768; }
        else if (idx < 131072) { src = Wrel1;  dst = T2; kin = 256; e = idx - 65536; }
        else                   { src = Wroot1; dst = T3; kin = 256; e = idx - 131072; }
        int o = (kin == 128) ? (e >> 7) : (e >> 8);
        int i = e & (kin - 1);
        dst[e] = f2bf(src[(long)i * 256 + o]);
        return;
    }

    __shared__ unsigned short As[128 * LDH];
    __shared__ unsigned short Bs[128 * LDH];
    __shared__ float rsq[128];

    int tid = threadIdx.x;
    int lane = tid & 63;
    int wave = tid >> 6;
    int quad = lane >> 4, l16 = lane & 15;
    int wm = (wave >> 1) * 64, wn = (wave & 1) * 64;
    int m0 = (blockIdx.x - 896) * 128;

    f32x4 acc[4][4] = {};

    for (int k0 = 0; k0 < Ff; k0 += 32) {
        __syncthreads();
        #pragma unroll
        for (int l = 0; l < 2; ++l) {
            int idx = tid + l * 256;
            int r = idx >> 2, ch = idx & 3;
            const float* px = x + (long)(m0 + r) * Ff + k0 + ch * 8;
            float4 xa = *(const float4*)px;
            float4 xb = *(const float4*)(px + 4);
            ushort4v pa, pb;
            pa[0] = f2bf(xa.x); pa[1] = f2bf(xa.y); pa[2] = f2bf(xa.z); pa[3] = f2bf(xa.w);
            pb[0] = f2bf(xb.x); pb[1] = f2bf(xb.y); pb[2] = f2bf(xb.z); pb[3] = f2bf(xb.w);
            *(ushort4v*)&As[r * LDH + ch * 8] = pa;
            *(ushort4v*)&As[r * LDH + ch * 8 + 4] = pb;
            int kk = k0 + ch * 8;
            ushort4v qa, qb;
            #pragma unroll
            for (int u = 0; u < 4; ++u) qa[u] = f2bf(Wg[(long)(kk + u) * 128 + r]);
            #pragma unroll
            for (int u = 0; u < 4; ++u) qb[u] = f2bf(Wg[(long)(kk + 4 + u) * 128 + r]);
            *(ushort4v*)&Bs[r * LDH + ch * 8] = qa;
            *(ushort4v*)&Bs[r * LDH + ch * 8 + 4] = qb;
        }
        __syncthreads();
        bf16x8 af[4], bfr[4];
        #pragma unroll
        for (int i = 0; i < 4; ++i)
            af[i] = *(const bf16x8*)&As[(wm + i * 16 + l16) * LDH + quad * 8];
        #pragma unroll
        for (int j = 0; j < 4; ++j)
            bfr[j] = *(const bf16x8*)&Bs[(wn + j * 16 + l16) * LDH + quad * 8];
        #pragma unroll
        for (int i = 0; i < 4; ++i)
            #pragma unroll
            for (int j = 0; j < 4; ++j)
                acc[i][j] = __builtin_amdgcn_mfma_f32_16x16x32_bf16(
                    af[i], bfr[j], acc[i][j], 0, 0, 0);
    }

    if (tid < 128) rsq[tid] = 0.f;
    __syncthreads();

    #pragma unroll
    for (int i = 0; i < 4; ++i) {
        int lrow = wm + i * 16 + quad * 4;
        int mb = m0 + lrow;
        float rp0 = 0.f, rp1 = 0.f, rp2 = 0.f, rp3 = 0.f;
        #pragma unroll
        for (int j = 0; j < 4; ++j) {
            int n = wn + j * 16 + l16;
            f32x4 v = acc[i][j];
            float bv = bg[n];
            unsigned short s0 = f2bf(v[0] + bv), s1 = f2bf(v[1] + bv);
            unsigned short s2 = f2bf(v[2] + bv), s3 = f2bf(v[3] + bv);
            h0b[(long)(mb + 0) * Ff + n] = s0;
            h0b[(long)(mb + 1) * Ff + n] = s1;
            h0b[(long)(mb + 2) * Ff + n] = s2;
            h0b[(long)(mb + 3) * Ff + n] = s3;
            ushort4v p; p[0] = s0; p[1] = s1; p[2] = s2; p[3] = s3;
            long ti = ((long)(mb >> 9) * Ff + n) * 512 + (mb & 511);
            *(ushort4v*)&h0T[ti] = p;
            float f0 = bf2f(s0), f1 = bf2f(s1), f2 = bf2f(s2), f3 = bf2f(s3);
            rp0 += f0 * f0; rp1 += f1 * f1; rp2 += f2 * f2; rp3 += f3 * f3;
        }
        #pragma unroll
        for (int m = 1; m < 16; m <<= 1) {
            rp0 += __shfl_xor(rp0, m);
            rp1 += __shfl_xor(rp1, m);
            rp2 += __shfl_xor(rp2, m);
            rp3 += __shfl_xor(rp3, m);
        }
        if (l16 == 0) {
            atomicAdd(&rsq[lrow + 0], rp0);
            atomicAdd(&rsq[lrow + 1], rp1);
            atomicAdd(&rsq[lrow + 2], rp2);
            atomicAdd(&rsq[lrow + 3], rp3);
        }
    }
    __syncthreads();
    if (tid < 128) sqv[m0 + tid] = rsq[tid];
}

// ---------------- Gram -> adjacency A via MFMA, SYMMETRY-EXPLOITING -------------
// A is symmetric: compute only 10 of 16 quadrant tiles (4 diag + 6 upper).
// Upper tile written fully coalesced via an LDS bounce; mirror tile written via
// the direct packed path. Row sums for both sides accumulated into w.
__global__ __launch_bounds__(512) void gram_A_sym(
    const unsigned short* __restrict__ h0b, const float* __restrict__ sqv,
    const float* __restrict__ sigma, unsigned short* __restrict__ Aout,
    float* __restrict__ w)
{
    int id = blockIdx.x;
    int b = id & 63;
    int tp = id >> 6;                 // 0..9
    int ti, tj;
    if      (tp < 4) { ti = 0; tj = tp; }
    else if (tp < 7) { ti = 1; tj = tp - 3; }
    else if (tp < 9) { ti = 2; tj = tp - 5; }
    else             { ti = 3; tj = 3; }
    int i0 = ti * 128, j0 = tj * 128;
    bool offd = (ti != tj);

    const unsigned short* H = h0b + (long)b * Nn * Ff;
    const float* SQ = sqv + (long)b * Nn;
    unsigned short* Ab = Aout + (long)b * Nn * Nn;

    // POOL: staging (Is=POOL[0..8191], Js=POOL[8192..16383]) then reused as
    // Atile[128][ATP] (16896 shorts) in the epilogue.
    __shared__ unsigned short POOL[128 * ATP];
    __shared__ float rsI[128];
    __shared__ float rsJ[128];

    int tid = threadIdx.x;
    int lane = tid & 63;
    int wave = tid >> 6;
    int quad = lane >> 4, l16 = lane & 15;
    int wm = (wave >> 1) * 32, wn = (wave & 1) * 64;
    int sr = lane >> 2, sc = lane & 3;

    unsigned short* Is = POOL;
    unsigned short* Js = POOL + 8192;

    f32x4 acc[2][4] = {};

    auto issue = [&](int g) {
        int kk = g << 5;
        unsigned short* Id = Is + (g & 1) * 4096;
        unsigned short* Jd = Js + (g & 1) * 4096;
        int r = wave * 16 + sr;
        int c = sc ^ SWZ(r);
        async_ld16(H + (long)(i0 + r) * Ff + kk + c * 8, Id + (wave * 16) * 32);
        async_ld16(H + (long)(j0 + r) * Ff + kk + c * 8, Jd + (wave * 16) * 32);
    };

    issue(0);
    for (int g = 0; g < (Ff >> 5); ++g) {
        __syncthreads();
        if (g + 1 < (Ff >> 5)) issue(g + 1);
        const unsigned short* Ib = Is + (g & 1) * 4096;
        const unsigned short* Jb = Js + (g & 1) * 4096;
        bf16x8 af[2], bfr[4];
        #pragma unroll
        for (int i = 0; i < 2; ++i) {
            int r = wm + i * 16 + l16;
            af[i] = *(const bf16x8*)&Ib[r * 32 + (quad ^ SWZ(r)) * 8];
        }
        #pragma unroll
        for (int j = 0; j < 4; ++j) {
            int r = wn + j * 16 + l16;
            bfr[j] = *(const bf16x8*)&Jb[r * 32 + (quad ^ SWZ(r)) * 8];
        }
        #pragma unroll
        for (int i = 0; i < 2; ++i)
            #pragma unroll
            for (int j = 0; j < 4; ++j)
                acc[i][j] = __builtin_amdgcn_mfma_f32_16x16x32_bf16(
                    af[i], bfr[j], acc[i][j], 0, 0, 0);
    }

    if (tid < 128) { rsI[tid] = 0.f; rsJ[tid] = 0.f; }
    __syncthreads();   // all staging reads done -> POOL reusable as Atile

    unsigned short* AT = POOL;
    float s = sigma[0];
    float inv2s2 = 1.0f / (2.0f * s * s);
    float colsum0 = 0.f, colsum1 = 0.f, colsum2 = 0.f, colsum3 = 0.f;

    #pragma unroll
    for (int i = 0; i < 2; ++i) {
        int lrow = wm + i * 16 + quad * 4;      // tile-local row base
        int rbg = i0 + lrow;                     // global row base
        float rs0 = 0.f, rs1 = 0.f, rs2 = 0.f, rs3 = 0.f;
        #pragma unroll
        for (int j = 0; j < 4; ++j) {
            int cl = wn + j * 16 + l16;          // tile-local col
            int c = j0 + cl;                     // global col
            float sqc = SQ[c];
            f32x4 v = acc[i][j];
            ushort4v pk;
            float av[4];
            #pragma unroll
            for (int r4 = 0; r4 < 4; ++r4) {
                int r = rbg + r4;
                float d = fmaxf(SQ[r] + sqc - 2.0f * v[r4], 0.0f);
                unsigned short a = (r == c) ? (unsigned short)0
                                            : f2bf(__expf(-d * inv2s2));
                pk[r4] = a;
                av[r4] = bf2f(a);
                AT[(lrow + r4) * ATP + cl] = a;   // tile-local [row][col]
            }
            if (offd)   // mirror tile A[c][rbg..rbg+3], packed 8B (direct path)
                *(ushort4v*)&Ab[(long)c * Nn + rbg] = pk;
            float cs = av[0] + av[1] + av[2] + av[3];
            if (j == 0) colsum0 += cs;
            else if (j == 1) colsum1 += cs;
            else if (j == 2) colsum2 += cs;
            else colsum3 += cs;
            rs0 += av[0]; rs1 += av[1]; rs2 += av[2]; rs3 += av[3];
        }
        #pragma unroll
        for (int m = 1; m < 16; m <<= 1) {
            rs0 += __shfl_xor(rs0, m);
            rs1 += __shfl_xor(rs1, m);
            rs2 += __shfl_xor(rs2, m);
            rs3 += __shfl_xor(rs3, m);
        }
        if (l16 == 0) {
            atomicAdd(&rsI[lrow + 0], rs0);
            atomicAdd(&rsI[lrow + 1], rs1);
            atomicAdd(&rsI[lrow + 2], rs2);
            atomicAdd(&rsI[lrow + 3], rs3);
        }
    }

    if (offd) {   // column sums -> mirror-row sums
        #pragma unroll
        for (int j = 0; j < 4; ++j) {
            float cs = (j == 0) ? colsum0 : (j == 1) ? colsum1
                     : (j == 2) ? colsum2 : colsum3;
            cs += __shfl_xor(cs, 16);
            cs += __shfl_xor(cs, 32);
            if (lane < 16)
                atomicAdd(&rsJ[wn + j * 16 + l16], cs);
        }
    }
    __syncthreads();   // AT + rsI/rsJ complete

    // coalesced row-major write of the (i0,j0) tile
    {
        int row0 = tid >> 4, part = tid & 15;
        #pragma unroll
        for (int rr = 0; rr < 4; ++rr) {
            int row = row0 + rr * 32;
            ushort4v u0 = *(const ushort4v*)&AT[row * ATP + part * 8];
            ushort4v u1 = *(const ushort4v*)&AT[row * ATP + part * 8 + 4];
            unsigned short* gp = &Ab[(long)(i0 + row) * Nn + j0 + part * 8];
            *(ushort4v*)gp = u0;
            *(ushort4v*)(gp + 4) = u1;
        }
    }
    if (tid < 128) {
        atomicAdd(&w[(long)b * Nn + i0 + tid], rsI[tid]);
        if (offd) atomicAdd(&w[(long)b * Nn + j0 + tid], rsJ[tid]);
    }
}

// ---------------- head: sum 8 nodeblock partials + layer2-collapse + mean + MLP ----
__global__ __launch_bounds__(256) void head_kernel(
    const float* __restrict__ vpart, const float* __restrict__ mpart,
    const float* __restrict__ Wrel2, const float* __restrict__ Wroot2,
    const float* __restrict__ brel2,
    const float* __restrict__ W1, const float* __restrict__ b1,
    const float* __restrict__ Wout, const float* __restrict__ bout,
    float* __restrict__ out)
{
    int b = blockIdx.x;
    int j = threadIdx.x;
    __shared__ float vs[Hh], ms[Hh], gs[Hh], g2[Hh];
    float vp = 0.f, mp = 0.f;
    #pragma unroll
    for (int p = 0; p < 8; ++p) {
        long o = ((long)(b * 8 + p)) * Hh + j;
        vp += vpart[o];
        mp += mpart[o];
    }
    vs[j] = vp * (1.0f / (float)Nn);
    ms[j] = mp * (1.0f / (float)Nn);
    __syncthreads();
    float s = brel2[j];
    for (int c = 0; c < Hh; ++c)
        s += vs[c] * Wrel2[c * Hh + j] + ms[c] * Wroot2[c * Hh + j];
    gs[j] = s;
    __syncthreads();
    float t = b1[j];
    for (int k = 0; k < Hh; ++k) t += gs[k] * W1[k * Hh + j];
    g2[j] = fmaxf(t, 0.f);
    __syncthreads();
    if (j < OUTD) {
        float s2 = bout[j];
        for (int k = 0; k < Hh; ++k) s2 += g2[k] * Wout[k * OUTD + j];
        out[b * OUTD + j] = s2;
    }
}

extern "C" void kernel_launch(void* const* d_in, const int* in_sizes, int n_in,
                              void* d_out, int out_size, void* d_ws, size_t ws_size,
                              hipStream_t stream) {
    const float* x      = (const float*)d_in[0];
    const float* sigma  = (const float*)d_in[4];
    const float* Wg     = (const float*)d_in[5];
    const float* bg     = (const float*)d_in[6];
    const float* Wrel0  = (const float*)d_in[7];
    const float* Wroot0 = (const float*)d_in[8];
    const float* brel0  = (const float*)d_in[9];
    const float* Wrel1  = (const float*)d_in[10];
    const float* Wroot1 = (const float*)d_in[11];
    const float* brel1  = (const float*)d_in[12];
    const float* Wrel2  = (const float*)d_in[13];
    const float* Wroot2 = (const float*)d_in[14];
    const float* brel2  = (const float*)d_in[15];
    const float* W1     = (const float*)d_in[16];
    const float* b1     = (const float*)d_in[17];
    const float* Wout   = (const float*)d_in[18];
    const float* bout   = (const float*)d_in[19];
    float* out = (float*)d_out;

    // Workspace layout (bytes)
    char* ws = (char*)d_ws;
    unsigned short* h0b  = (unsigned short*)(ws + 16777216);
    unsigned short* h0T  = (unsigned short*)(ws + 25165824);
    float*          sq   = (float*)(ws + 33554432);
    unsigned short* Aadj = (unsigned short*)(ws + 33685504);
    unsigned short* h1b  = (unsigned short*)(ws + 84017152);
    unsigned short* h1T  = (unsigned short*)(ws + 100794368);
    unsigned short* WrelT0  = (unsigned short*)(ws + 167903232);
    unsigned short* WrootT0 = (unsigned short*)(ws + 167968768);
    unsigned short* WrelT1  = (unsigned short*)(ws + 168034304);
    unsigned short* WrootT1 = (unsigned short*)(ws + 168165376);
    float*          w     = (float*)(ws + 168558592);
    float*          vpart = (float*)(ws + 168689664);
    float*          mpart = (float*)(ws + 169213952);

    // prep (weights + w zero) and h0 in one dispatch
    prep_h0<<<1152, 256, 0, stream>>>(x, Wg, bg, Wrel0, Wroot0, Wrel1, Wroot1,
                                      WrelT0, WrootT0, WrelT1, WrootT1,
                                      w, h0b, h0T, sq);

    // A = exp(-dist/(2 sigma^2)), zero diag; symmetric: 10 tiles/graph
    gram_A_sym<<<dim3(10 * Bsz, 1, 1), 512, 0, stream>>>(h0b, sq, sigma, Aadj, w);

    // ---- layer 0: fused A@h + dense (counted-vmcnt pipeline) ----
    fused_l0<<<dim3(4 * Bsz, 1, 1), 512, 0, stream>>>(
        h0T, Aadj, h0b, WrelT0, WrootT0, brel0, h1b, h1T);

    // ---- layer 1 + dense + layer-2-collapse pooling ----
    fused_l1<<<dim3(4 * Bsz, 1, 1), 512, 0, stream>>>(
        h1T, Aadj, h1b, WrelT1, WrootT1, brel1, w, vpart, mpart);

    // head
    head_kernel<<<Bsz, 256, 0, stream>>>(vpart, mpart, Wrel2, Wroot2, brel2,
                                         W1, b1, Wout, bout, out);
}

// Round 6
// 207.648 us; speedup vs baseline: 3.2558x; 1.0042x over previous
//
#include <hip/hip_runtime.h>
#include <math.h>

// Problem constants
#define Bsz 64
#define Nn 512
#define Ff 128
#define Hh 256
#define OUTD 6
#define MTOT (Bsz * Nn)   // 32768

typedef __bf16 bf16x8 __attribute__((ext_vector_type(8)));
typedef float f32x4 __attribute__((ext_vector_type(4)));
typedef unsigned short ushort4v __attribute__((ext_vector_type(4)));

__device__ __forceinline__ unsigned short f2bf(float f) {
    unsigned u = __float_as_uint(f);
    u += 0x7FFFu + ((u >> 16) & 1u);        // RNE
    return (unsigned short)(u >> 16);
}
__device__ __forceinline__ float bf2f(unsigned short s) {
    return __uint_as_float(((unsigned)s) << 16);
}

// XOR swizzle of the 16B k-chunk within a 64B LDS row (kills ds_read_b128 bank conflicts)
#define SWZ(r) (((r) ^ ((r) >> 2)) & 3)

// async 16B global->LDS (DMA; LDS dest = wave-uniform base + lane*16)
__device__ __forceinline__ void async_ld16(const unsigned short* g, unsigned short* l) {
    __builtin_amdgcn_global_load_lds(
        (const __attribute__((address_space(1))) void*)g,
        (__attribute__((address_space(3))) void*)l,
        16, 0, 0);
}

// counted vmcnt wait
__device__ __forceinline__ void wait_vm(int n) {
    switch (n) {
        case 0: asm volatile("s_waitcnt vmcnt(0)" ::: "memory"); break;
        case 1: asm volatile("s_waitcnt vmcnt(1)" ::: "memory"); break;
        case 2: asm volatile("s_waitcnt vmcnt(2)" ::: "memory"); break;
        case 3: asm volatile("s_waitcnt vmcnt(3)" ::: "memory"); break;
        case 4: asm volatile("s_waitcnt vmcnt(4)" ::: "memory"); break;
        case 5: asm volatile("s_waitcnt vmcnt(5)" ::: "memory"); break;
        default: asm volatile("s_waitcnt vmcnt(6)" ::: "memory"); break;
    }
}
__device__ __forceinline__ void pipe_barrier(int n) {
    wait_vm(n);
    __builtin_amdgcn_s_barrier();
    __builtin_amdgcn_sched_barrier(0);
}

#define LDH 40           // padded LDS row stride (bf16) for the non-async h0 kernel
#define TSZ (128 * 32)   // one LDS tile: 128 rows x 32 bf16 (8 KB)
#define ATS (256 * 32)   // one LDS A-tile: 256 rows x 32 bf16 (16 KB)
#define ATP 132          // gram Atile LDS row stride (128 + 4 pad, 8B-aligned rows)

// agg tile index: [kt][node][32] with chunk-XOR swizzle -> reads bank-match the
// conflict-free staging tiles (row stride 64B, start banks alternate 0/16,
// quad^SWZ spreads the chunk) instead of the old padded layout's 8-way alias.
__device__ __forceinline__ int agg_idx(int kt, int nl, int fo) {
    return kt * 4096 + nl * 32 + ((((fo >> 3) & 3) ^ SWZ(nl)) << 3) + (fo & 7);
}

// ---------------- FUSED layer 0: A@h (K=512) + dense (K=128+128) -----------------
__global__ __launch_bounds__(512) void fused_l0(
    const unsigned short* __restrict__ h0T,   // [graph][128][512]
    const unsigned short* __restrict__ Arows, // [graph][512][512]
    const unsigned short* __restrict__ h0b,   // [node][128]
    const unsigned short* __restrict__ WrelT0,  // [256][128]
    const unsigned short* __restrict__ WrootT0, // [256][128]
    const float* __restrict__ brel0,
    unsigned short* __restrict__ h1b,  // [node][256]
    unsigned short* __restrict__ h1T)  // [graph][256][512]
{
    int id = blockIdx.x;
    int b = id & 63;               // graph (XCD locality)
    int nt = id >> 6;              // node tile 0..3
    int n0g = nt * 128;
    long nodeBase = (long)b * Nn + n0g;

    const unsigned short* HT = h0T + (long)b * Ff * Nn;
    const unsigned short* AR = Arows + (long)b * Nn * Nn;

    __shared__ unsigned short SA[3 * ATS];        // 48 KB
    __shared__ unsigned short SB[3 * TSZ];        // 24 KB
    __shared__ unsigned short AGK[4 * 128 * 32];  // 32 KB agg [kt][node][32] swz

    int tid = threadIdx.x;
    int lane = tid & 63;
    int wave = tid >> 6;
    int quad = lane >> 4, l16 = lane & 15;
    int sr = lane >> 2, sc = lane & 3;

    // ---------- stage 1: agg tile = A@h0 (M=128 feats, N=128 nodes, K=512) ----------
    {
        int wm = (wave >> 1) * 32, wn = (wave & 1) * 64;
        f32x4 acc[2][4] = {};
        auto issue = [&](int g) {
            int kk = g << 5;
            unsigned short* Ad = SA + (g % 3) * ATS;
            unsigned short* Bd = SB + (g % 3) * TSZ;
            int r = wave * 16 + sr;
            int c = sc ^ SWZ(r);
            async_ld16(HT + (long)r * Nn + kk + c * 8, Ad + (wave * 16) * 32);
            async_ld16(AR + (long)(n0g + r) * Nn + kk + c * 8, Bd + (wave * 16) * 32);
        };
        issue(0); issue(1);
        for (int g = 0; g < 16; ++g) {
            pipe_barrier(g + 1 < 16 ? 2 : 0);
            if (g + 2 < 16) issue(g + 2);
            const unsigned short* Ab = SA + (g % 3) * ATS;
            const unsigned short* Bb = SB + (g % 3) * TSZ;
            bf16x8 af[2], bfr[4];
            #pragma unroll
            for (int i = 0; i < 2; ++i) {
                int r = wm + i * 16 + l16;
                af[i] = *(const bf16x8*)&Ab[r * 32 + (quad ^ SWZ(r)) * 8];
            }
            #pragma unroll
            for (int j = 0; j < 4; ++j) {
                int r = wn + j * 16 + l16;
                bfr[j] = *(const bf16x8*)&Bb[r * 32 + (quad ^ SWZ(r)) * 8];
            }
            #pragma unroll
            for (int i = 0; i < 2; ++i)
                #pragma unroll
                for (int j = 0; j < 4; ++j)
                    acc[i][j] = __builtin_amdgcn_mfma_f32_16x16x32_bf16(
                        af[i], bfr[j], acc[i][j], 0, 0, 0);
        }
        #pragma unroll
        for (int i = 0; i < 2; ++i) {
            int f = wm + i * 16 + quad * 4;
            int kt = f >> 5, fo = f & 31;
            #pragma unroll
            for (int j = 0; j < 4; ++j) {
                int nl = wn + j * 16 + l16;
                f32x4 v = acc[i][j];
                ushort4v p;
                p[0] = f2bf(v[0]); p[1] = f2bf(v[1]);
                p[2] = f2bf(v[2]); p[3] = f2bf(v[3]);
                *(ushort4v*)&AGK[agg_idx(kt, nl, fo)] = p;
            }
        }
    }
    __syncthreads();

    // ---------- stage 2: dense, M=256 outfeats x N=128 nodes, wave tile 64x64 ----------
    {
        int wm = (wave >> 1) * 64, wn = (wave & 1) * 64;
        f32x4 acc[4][4] = {};
        auto issue2 = [&](int g) {
            const unsigned short* Wp = (g < 4) ? WrelT0 : WrootT0;
            int kk = (g & 3) << 5;
            unsigned short* Ad = SA + (g % 3) * ATS;
            int r = wave * 16 + sr;
            int c = sc ^ SWZ(r);
            async_ld16(Wp + (long)r * Ff + kk + c * 8, Ad + (wave * 16) * 32);
            int r2 = 128 + r;
            int c2 = sc ^ SWZ(r2);
            async_ld16(Wp + (long)r2 * Ff + kk + c2 * 8, Ad + (128 + wave * 16) * 32);
            if (g >= 4) {
                unsigned short* Bd = SB + (g % 3) * TSZ;
                async_ld16(h0b + (nodeBase + r) * Ff + kk + c * 8,
                           Bd + (wave * 16) * 32);
            }
        };
        issue2(0); issue2(1);
        for (int g = 0; g < 8; ++g) {
            int nx = g + 1;
            pipe_barrier(nx >= 8 ? 0 : (nx < 4 ? 2 : 3));
            if (g + 2 < 8) issue2(g + 2);
            const unsigned short* Ab = SA + (g % 3) * ATS;
            bf16x8 af[4], bfr[4];
            #pragma unroll
            for (int i = 0; i < 4; ++i) {
                int r = wm + i * 16 + l16;
                af[i] = *(const bf16x8*)&Ab[r * 32 + (quad ^ SWZ(r)) * 8];
            }
            if (g < 4) {
                #pragma unroll
                for (int j = 0; j < 4; ++j) {
                    int nl = wn + j * 16 + l16;
                    bfr[j] = *(const bf16x8*)&AGK[agg_idx(g, nl, quad * 8)];
                }
            } else {
                const unsigned short* Bb = SB + (g % 3) * TSZ;
                #pragma unroll
                for (int j = 0; j < 4; ++j) {
                    int r = wn + j * 16 + l16;
                    bfr[j] = *(const bf16x8*)&Bb[r * 32 + (quad ^ SWZ(r)) * 8];
                }
            }
            #pragma unroll
            for (int i = 0; i < 4; ++i)
                #pragma unroll
                for (int j = 0; j < 4; ++j)
                    acc[i][j] = __builtin_amdgcn_mfma_f32_16x16x32_bf16(
                        af[i], bfr[j], acc[i][j], 0, 0, 0);
        }
        #pragma unroll
        for (int i = 0; i < 4; ++i) {
            int of = wm + i * 16 + quad * 4;
            float b0 = brel0[of + 0], b1 = brel0[of + 1];
            float b2 = brel0[of + 2], b3 = brel0[of + 3];
            #pragma unroll
            for (int j = 0; j < 4; ++j) {
                int nl = wn + j * 16 + l16;
                f32x4 v = acc[i][j];
                float o0 = fmaxf(v[0] + b0, 0.f), o1 = fmaxf(v[1] + b1, 0.f);
                float o2 = fmaxf(v[2] + b2, 0.f), o3 = fmaxf(v[3] + b3, 0.f);
                ushort4v p;
                p[0] = f2bf(o0); p[1] = f2bf(o1); p[2] = f2bf(o2); p[3] = f2bf(o3);
                *(ushort4v*)&h1b[(nodeBase + nl) * Hh + of] = p;
                long base = ((long)b * Hh) * 512 + n0g + nl;
                h1T[base + (long)(of + 0) * 512] = p[0];
                h1T[base + (long)(of + 1) * 512] = p[1];
                h1T[base + (long)(of + 2) * 512] = p[2];
                h1T[base + (long)(of + 3) * 512] = p[3];
            }
        }
    }
}

// ---------------- FUSED layer 1 + layer-2-collapse pooling -----------------------
__global__ __launch_bounds__(512) void fused_l1(
    const unsigned short* __restrict__ h1T,   // [graph][256][512]
    const unsigned short* __restrict__ Arows, // [graph][512][512]
    const unsigned short* __restrict__ h1b,   // [node][256]
    const unsigned short* __restrict__ WrelT1,  // [256][256]
    const unsigned short* __restrict__ WrootT1, // [256][256]
    const float* __restrict__ brel1,
    const float* __restrict__ w,
    float* __restrict__ vpart, float* __restrict__ mpart)  // [512][256]
{
    constexpr int BTS = 128 * 32;   // B-op tile shorts (8 KB)

    int id = blockIdx.x;
    int b = id & 63;               // graph
    int nt = id >> 6;              // node tile 0..3
    int n0g = nt * 128;
    long nodeBase = (long)b * Nn + n0g;

    const unsigned short* HT = h1T + (long)b * Hh * Nn;
    const unsigned short* AR = Arows + (long)b * Nn * Nn;

    __shared__ unsigned short SA[3 * ATS];        // 48 KB
    __shared__ unsigned short SB[3 * BTS];        // 24 KB
    __shared__ unsigned short AGK[8 * 128 * 32];  // 64 KB agg [kt][node][32] swz

    int tid = threadIdx.x;
    int lane = tid & 63;
    int wave = tid >> 6;
    int quad = lane >> 4, l16 = lane & 15;
    int wm = (wave >> 1) * 64;
    int wn = (wave & 1) * 64;
    int sr = lane >> 2, sc = lane & 3;

    // ---------- stage 1: aggT (M=256 feats, N=128 nodes, K=512) ----------
    {
        f32x4 acc[4][4] = {};
        auto issue = [&](int g) {
            int kk = g << 5;
            unsigned short* Ad = SA + (g % 3) * ATS;
            int r = wave * 16 + sr;
            int c = sc ^ SWZ(r);
            async_ld16(HT + (long)r * Nn + kk + c * 8, Ad + (wave * 16) * 32);
            int r2 = 128 + r;
            int c2 = sc ^ SWZ(r2);
            async_ld16(HT + (long)r2 * Nn + kk + c2 * 8, Ad + (128 + wave * 16) * 32);
            unsigned short* Bd = SB + (g % 3) * BTS;
            async_ld16(AR + (long)(n0g + r) * Nn + kk + c * 8, Bd + (wave * 16) * 32);
        };
        issue(0); issue(1);
        for (int g = 0; g < 16; ++g) {
            pipe_barrier(g + 1 < 16 ? 3 : 0);
            if (g + 2 < 16) issue(g + 2);
            const unsigned short* Ab = SA + (g % 3) * ATS;
            const unsigned short* Bb = SB + (g % 3) * BTS;
            bf16x8 af[4], bfr[4];
            #pragma unroll
            for (int i = 0; i < 4; ++i) {
                int r = wm + i * 16 + l16;
                af[i] = *(const bf16x8*)&Ab[r * 32 + (quad ^ SWZ(r)) * 8];
            }
            #pragma unroll
            for (int j = 0; j < 4; ++j) {
                int r = wn + j * 16 + l16;
                bfr[j] = *(const bf16x8*)&Bb[r * 32 + (quad ^ SWZ(r)) * 8];
            }
            #pragma unroll
            for (int i = 0; i < 4; ++i)
                #pragma unroll
                for (int j = 0; j < 4; ++j)
                    acc[i][j] = __builtin_amdgcn_mfma_f32_16x16x32_bf16(
                        af[i], bfr[j], acc[i][j], 0, 0, 0);
        }
        #pragma unroll
        for (int i = 0; i < 4; ++i) {
            int f = wm + i * 16 + quad * 4;
            int kt = f >> 5, fo = f & 31;
            #pragma unroll
            for (int j = 0; j < 4; ++j) {
                int nl = wn + j * 16 + l16;
                f32x4 v = acc[i][j];
                ushort4v p;
                p[0] = f2bf(v[0]); p[1] = f2bf(v[1]);
                p[2] = f2bf(v[2]); p[3] = f2bf(v[3]);
                *(ushort4v*)&AGK[agg_idx(kt, nl, fo)] = p;
            }
        }
    }
    __syncthreads();

    // ---------- stage 2: dense (M=256 outfeats, N=128 nodes, K=256+256) ----------
    f32x4 acc[4][4] = {};
    auto issue2 = [&](int g) {
        const unsigned short* Wp = (g < 8) ? WrelT1 : WrootT1;
        int kk = (g & 7) << 5;
        unsigned short* Ad = SA + (g % 3) * ATS;
        int r = wave * 16 + sr;
        int c = sc ^ SWZ(r);
        async_ld16(Wp + (long)r * Hh + kk + c * 8, Ad + (wave * 16) * 32);
        int r2 = 128 + r;
        int c2 = sc ^ SWZ(r2);
        async_ld16(Wp + (long)r2 * Hh + kk + c2 * 8, Ad + (128 + wave * 16) * 32);
        if (g >= 8) {
            unsigned short* Bd = SB + (g % 3) * BTS;
            async_ld16(h1b + (nodeBase + r) * Hh + kk + c * 8, Bd + (wave * 16) * 32);
        }
    };
    issue2(0); issue2(1);
    for (int g = 0; g < 16; ++g) {
        int nx = g + 1;
        pipe_barrier(nx >= 16 ? 0 : (nx < 8 ? 2 : 3));
        if (g + 2 < 16) issue2(g + 2);
        const unsigned short* Ab = SA + (g % 3) * ATS;
        bf16x8 af[4], bfr[4];
        #pragma unroll
        for (int i = 0; i < 4; ++i) {
            int r = wm + i * 16 + l16;
            af[i] = *(const bf16x8*)&Ab[r * 32 + (quad ^ SWZ(r)) * 8];
        }
        if (g < 8) {
            #pragma unroll
            for (int j = 0; j < 4; ++j) {
                int nl = wn + j * 16 + l16;
                bfr[j] = *(const bf16x8*)&AGK[agg_idx(g, nl, quad * 8)];
            }
        } else {
            const unsigned short* Bb = SB + (g % 3) * BTS;
            #pragma unroll
            for (int j = 0; j < 4; ++j) {
                int r = wn + j * 16 + l16;
                bfr[j] = *(const bf16x8*)&Bb[r * 32 + (quad ^ SWZ(r)) * 8];
            }
        }
        #pragma unroll
        for (int i = 0; i < 4; ++i)
            #pragma unroll
            for (int j = 0; j < 4; ++j)
                acc[i][j] = __builtin_amdgcn_mfma_f32_16x16x32_bf16(
                    af[i], bfr[j], acc[i][j], 0, 0, 0);
    }

    #pragma unroll
    for (int i = 0; i < 4; ++i) {
        int lf = wm + i * 16 + quad * 4;
        float b0 = brel1[lf + 0], b1 = brel1[lf + 1];
        float b2 = brel1[lf + 2], b3 = brel1[lf + 3];
        float vp0 = 0.f, vp1 = 0.f, vp2 = 0.f, vp3 = 0.f;
        float mp0 = 0.f, mp1 = 0.f, mp2 = 0.f, mp3 = 0.f;
        #pragma unroll
        for (int j = 0; j < 4; ++j) {
            long node = nodeBase + wn + j * 16 + l16;
            f32x4 v = acc[i][j];
            float o0 = fmaxf(v[0] + b0, 0.f), o1 = fmaxf(v[1] + b1, 0.f);
            float o2 = fmaxf(v[2] + b2, 0.f), o3 = fmaxf(v[3] + b3, 0.f);
            float h0v = bf2f(f2bf(o0)), h1v = bf2f(f2bf(o1));
            float h2v = bf2f(f2bf(o2)), h3v = bf2f(f2bf(o3));
            float wv = w[node];
            vp0 += wv * h0v; vp1 += wv * h1v; vp2 += wv * h2v; vp3 += wv * h3v;
            mp0 += h0v; mp1 += h1v; mp2 += h2v; mp3 += h3v;
        }
        #pragma unroll
        for (int m = 1; m < 16; m <<= 1) {
            vp0 += __shfl_xor(vp0, m); vp1 += __shfl_xor(vp1, m);
            vp2 += __shfl_xor(vp2, m); vp3 += __shfl_xor(vp3, m);
            mp0 += __shfl_xor(mp0, m); mp1 += __shfl_xor(mp1, m);
            mp2 += __shfl_xor(mp2, m); mp3 += __shfl_xor(mp3, m);
        }
        if (l16 == 0) {
            long o = ((long)(b * 8 + nt * 2 + (wave & 1))) * Hh + lf;
            float4 vv = {vp0, vp1, vp2, vp3};
            float4 mm = {mp0, mp1, mp2, mp3};
            *(float4*)&vpart[o] = vv;
            *(float4*)&mpart[o] = mm;
        }
    }
}

// ---------------- prep: weight convert/transpose + w zero + h0 MFMA ------------
__global__ __launch_bounds__(256) void prep_h0(
    const float* __restrict__ x, const float* __restrict__ Wg,
    const float* __restrict__ bg,
    const float* __restrict__ Wrel0, const float* __restrict__ Wroot0,
    const float* __restrict__ Wrel1, const float* __restrict__ Wroot1,
    unsigned short* __restrict__ T0, unsigned short* __restrict__ T1,
    unsigned short* __restrict__ T2, unsigned short* __restrict__ T3,
    float* __restrict__ w,
    unsigned short* __restrict__ h0b, unsigned short* __restrict__ h0T,
    float* __restrict__ sqv)
{
    if (blockIdx.x < 896) {
        int idx = blockIdx.x * 256 + threadIdx.x;
        if (idx >= 196608) { w[idx - 196608] = 0.f; return; }
        const float* src; unsigned short* dst; int kin; int e;
        if      (idx <  32768) { src = Wrel0;  dst = T0; kin = 128; e = idx; }
        else if (idx <  65536) { src = Wroot0; dst = T1; kin = 128; e = idx - 32768; }
        else if (idx < 131072) { src = Wrel1;  dst = T2; kin = 256; e = idx - 65536; }
        else                   { src = Wroot1; dst = T3; kin = 256; e = idx - 131072; }
        int o = (kin == 128) ? (e >> 7) : (e >> 8);
        int i = e & (kin - 1);
        dst[e] = f2bf(src[(long)i * 256 + o]);
        return;
    }

    __shared__ unsigned short As[128 * LDH];
    __shared__ unsigned short Bs[128 * LDH];
    __shared__ float rsq[128];

    int tid = threadIdx.x;
    int lane = tid & 63;
    int wave = tid >> 6;
    int quad = lane >> 4, l16 = lane & 15;
    int wm = (wave >> 1) * 64, wn = (wave & 1) * 64;
    int m0 = (blockIdx.x - 896) * 128;

    f32x4 acc[4][4] = {};

    for (int k0 = 0; k0 < Ff; k0 += 32) {
        __syncthreads();
        #pragma unroll
        for (int l = 0; l < 2; ++l) {
            int idx = tid + l * 256;
            int r = idx >> 2, ch = idx & 3;
            const float* px = x + (long)(m0 + r) * Ff + k0 + ch * 8;
            float4 xa = *(const float4*)px;
            float4 xb = *(const float4*)(px + 4);
            ushort4v pa, pb;
            pa[0] = f2bf(xa.x); pa[1] = f2bf(xa.y); pa[2] = f2bf(xa.z); pa[3] = f2bf(xa.w);
            pb[0] = f2bf(xb.x); pb[1] = f2bf(xb.y); pb[2] = f2bf(xb.z); pb[3] = f2bf(xb.w);
            *(ushort4v*)&As[r * LDH + ch * 8] = pa;
            *(ushort4v*)&As[r * LDH + ch * 8 + 4] = pb;
            int kk = k0 + ch * 8;
            ushort4v qa, qb;
            #pragma unroll
            for (int u = 0; u < 4; ++u) qa[u] = f2bf(Wg[(long)(kk + u) * 128 + r]);
            #pragma unroll
            for (int u = 0; u < 4; ++u) qb[u] = f2bf(Wg[(long)(kk + 4 + u) * 128 + r]);
            *(ushort4v*)&Bs[r * LDH + ch * 8] = qa;
            *(ushort4v*)&Bs[r * LDH + ch * 8 + 4] = qb;
        }
        __syncthreads();
        bf16x8 af[4], bfr[4];
        #pragma unroll
        for (int i = 0; i < 4; ++i)
            af[i] = *(const bf16x8*)&As[(wm + i * 16 + l16) * LDH + quad * 8];
        #pragma unroll
        for (int j = 0; j < 4; ++j)
            bfr[j] = *(const bf16x8*)&Bs[(wn + j * 16 + l16) * LDH + quad * 8];
        #pragma unroll
        for (int i = 0; i < 4; ++i)
            #pragma unroll
            for (int j = 0; j < 4; ++j)
                acc[i][j] = __builtin_amdgcn_mfma_f32_16x16x32_bf16(
                    af[i], bfr[j], acc[i][j], 0, 0, 0);
    }

    if (tid < 128) rsq[tid] = 0.f;
    __syncthreads();

    #pragma unroll
    for (int i = 0; i < 4; ++i) {
        int lrow = wm + i * 16 + quad * 4;
        int mb = m0 + lrow;
        float rp0 = 0.f, rp1 = 0.f, rp2 = 0.f, rp3 = 0.f;
        #pragma unroll
        for (int j = 0; j < 4; ++j) {
            int n = wn + j * 16 + l16;
            f32x4 v = acc[i][j];
            float bv = bg[n];
            unsigned short s0 = f2bf(v[0] + bv), s1 = f2bf(v[1] + bv);
            unsigned short s2 = f2bf(v[2] + bv), s3 = f2bf(v[3] + bv);
            h0b[(long)(mb + 0) * Ff + n] = s0;
            h0b[(long)(mb + 1) * Ff + n] = s1;
            h0b[(long)(mb + 2) * Ff + n] = s2;
            h0b[(long)(mb + 3) * Ff + n] = s3;
            ushort4v p; p[0] = s0; p[1] = s1; p[2] = s2; p[3] = s3;
            long ti = ((long)(mb >> 9) * Ff + n) * 512 + (mb & 511);
            *(ushort4v*)&h0T[ti] = p;
            float f0 = bf2f(s0), f1 = bf2f(s1), f2 = bf2f(s2), f3 = bf2f(s3);
            rp0 += f0 * f0; rp1 += f1 * f1; rp2 += f2 * f2; rp3 += f3 * f3;
        }
        #pragma unroll
        for (int m = 1; m < 16; m <<= 1) {
            rp0 += __shfl_xor(rp0, m);
            rp1 += __shfl_xor(rp1, m);
            rp2 += __shfl_xor(rp2, m);
            rp3 += __shfl_xor(rp3, m);
        }
        if (l16 == 0) {
            atomicAdd(&rsq[lrow + 0], rp0);
            atomicAdd(&rsq[lrow + 1], rp1);
            atomicAdd(&rsq[lrow + 2], rp2);
            atomicAdd(&rsq[lrow + 3], rp3);
        }
    }
    __syncthreads();
    if (tid < 128) sqv[m0 + tid] = rsq[tid];
}

// ---------------- Gram -> adjacency A via MFMA, SYMMETRY-EXPLOITING -------------
__global__ __launch_bounds__(512) void gram_A_sym(
    const unsigned short* __restrict__ h0b, const float* __restrict__ sqv,
    const float* __restrict__ sigma, unsigned short* __restrict__ Aout,
    float* __restrict__ w)
{
    int id = blockIdx.x;
    int b = id & 63;
    int tp = id >> 6;                 // 0..9
    int ti, tj;
    if      (tp < 4) { ti = 0; tj = tp; }
    else if (tp < 7) { ti = 1; tj = tp - 3; }
    else if (tp < 9) { ti = 2; tj = tp - 5; }
    else             { ti = 3; tj = 3; }
    int i0 = ti * 128, j0 = tj * 128;
    bool offd = (ti != tj);

    const unsigned short* H = h0b + (long)b * Nn * Ff;
    const float* SQ = sqv + (long)b * Nn;
    unsigned short* Ab = Aout + (long)b * Nn * Nn;

    __shared__ unsigned short POOL[128 * ATP];
    __shared__ float rsI[128];
    __shared__ float rsJ[128];

    int tid = threadIdx.x;
    int lane = tid & 63;
    int wave = tid >> 6;
    int quad = lane >> 4, l16 = lane & 15;
    int wm = (wave >> 1) * 32, wn = (wave & 1) * 64;
    int sr = lane >> 2, sc = lane & 3;

    unsigned short* Is = POOL;
    unsigned short* Js = POOL + 8192;

    f32x4 acc[2][4] = {};

    auto issue = [&](int g) {
        int kk = g << 5;
        unsigned short* Id = Is + (g & 1) * 4096;
        unsigned short* Jd = Js + (g & 1) * 4096;
        int r = wave * 16 + sr;
        int c = sc ^ SWZ(r);
        async_ld16(H + (long)(i0 + r) * Ff + kk + c * 8, Id + (wave * 16) * 32);
        async_ld16(H + (long)(j0 + r) * Ff + kk + c * 8, Jd + (wave * 16) * 32);
    };

    issue(0);
    for (int g = 0; g < (Ff >> 5); ++g) {
        __syncthreads();
        if (g + 1 < (Ff >> 5)) issue(g + 1);
        const unsigned short* Ib = Is + (g & 1) * 4096;
        const unsigned short* Jb = Js + (g & 1) * 4096;
        bf16x8 af[2], bfr[4];
        #pragma unroll
        for (int i = 0; i < 2; ++i) {
            int r = wm + i * 16 + l16;
            af[i] = *(const bf16x8*)&Ib[r * 32 + (quad ^ SWZ(r)) * 8];
        }
        #pragma unroll
        for (int j = 0; j < 4; ++j) {
            int r = wn + j * 16 + l16;
            bfr[j] = *(const bf16x8*)&Jb[r * 32 + (quad ^ SWZ(r)) * 8];
        }
        #pragma unroll
        for (int i = 0; i < 2; ++i)
            #pragma unroll
            for (int j = 0; j < 4; ++j)
                acc[i][j] = __builtin_amdgcn_mfma_f32_16x16x32_bf16(
                    af[i], bfr[j], acc[i][j], 0, 0, 0);
    }

    if (tid < 128) { rsI[tid] = 0.f; rsJ[tid] = 0.f; }
    __syncthreads();   // staging reads done -> POOL reusable as Atile

    unsigned short* AT = POOL;
    float s = sigma[0];
    float inv2s2 = 1.0f / (2.0f * s * s);
    float colsum0 = 0.f, colsum1 = 0.f, colsum2 = 0.f, colsum3 = 0.f;

    #pragma unroll
    for (int i = 0; i < 2; ++i) {
        int lrow = wm + i * 16 + quad * 4;
        int rbg = i0 + lrow;
        float rs0 = 0.f, rs1 = 0.f, rs2 = 0.f, rs3 = 0.f;
        #pragma unroll
        for (int j = 0; j < 4; ++j) {
            int cl = wn + j * 16 + l16;
            int c = j0 + cl;
            float sqc = SQ[c];
            f32x4 v = acc[i][j];
            ushort4v pk;
            float av[4];
            #pragma unroll
            for (int r4 = 0; r4 < 4; ++r4) {
                int r = rbg + r4;
                float d = fmaxf(SQ[r] + sqc - 2.0f * v[r4], 0.0f);
                unsigned short a = (r == c) ? (unsigned short)0
                                            : f2bf(__expf(-d * inv2s2));
                pk[r4] = a;
                av[r4] = bf2f(a);
                AT[(lrow + r4) * ATP + cl] = a;
            }
            if (offd)
                *(ushort4v*)&Ab[(long)c * Nn + rbg] = pk;
            float cs = av[0] + av[1] + av[2] + av[3];
            if (j == 0) colsum0 += cs;
            else if (j == 1) colsum1 += cs;
            else if (j == 2) colsum2 += cs;
            else colsum3 += cs;
            rs0 += av[0]; rs1 += av[1]; rs2 += av[2]; rs3 += av[3];
        }
        #pragma unroll
        for (int m = 1; m < 16; m <<= 1) {
            rs0 += __shfl_xor(rs0, m);
            rs1 += __shfl_xor(rs1, m);
            rs2 += __shfl_xor(rs2, m);
            rs3 += __shfl_xor(rs3, m);
        }
        if (l16 == 0) {
            atomicAdd(&rsI[lrow + 0], rs0);
            atomicAdd(&rsI[lrow + 1], rs1);
            atomicAdd(&rsI[lrow + 2], rs2);
            atomicAdd(&rsI[lrow + 3], rs3);
        }
    }

    if (offd) {
        #pragma unroll
        for (int j = 0; j < 4; ++j) {
            float cs = (j == 0) ? colsum0 : (j == 1) ? colsum1
                     : (j == 2) ? colsum2 : colsum3;
            cs += __shfl_xor(cs, 16);
            cs += __shfl_xor(cs, 32);
            if (lane < 16)
                atomicAdd(&rsJ[wn + j * 16 + l16], cs);
        }
    }
    __syncthreads();

    {
        int row0 = tid >> 4, part = tid & 15;
        #pragma unroll
        for (int rr = 0; rr < 4; ++rr) {
            int row = row0 + rr * 32;
            ushort4v u0 = *(const ushort4v*)&AT[row * ATP + part * 8];
            ushort4v u1 = *(const ushort4v*)&AT[row * ATP + part * 8 + 4];
            unsigned short* gp = &Ab[(long)(i0 + row) * Nn + j0 + part * 8];
            *(ushort4v*)gp = u0;
            *(ushort4v*)(gp + 4) = u1;
        }
    }
    if (tid < 128) {
        atomicAdd(&w[(long)b * Nn + i0 + tid], rsI[tid]);
        if (offd) atomicAdd(&w[(long)b * Nn + j0 + tid], rsJ[tid]);
    }
}

// ---------------- head: sum 8 nodeblock partials + layer2-collapse + mean + MLP ----
__global__ __launch_bounds__(256) void head_kernel(
    const float* __restrict__ vpart, const float* __restrict__ mpart,
    const float* __restrict__ Wrel2, const float* __restrict__ Wroot2,
    const float* __restrict__ brel2,
    const float* __restrict__ W1, const float* __restrict__ b1,
    const float* __restrict__ Wout, const float* __restrict__ bout,
    float* __restrict__ out)
{
    int b = blockIdx.x;
    int j = threadIdx.x;
    __shared__ float vs[Hh], ms[Hh], gs[Hh], g2[Hh];
    float vp = 0.f, mp = 0.f;
    #pragma unroll
    for (int p = 0; p < 8; ++p) {
        long o = ((long)(b * 8 + p)) * Hh + j;
        vp += vpart[o];
        mp += mpart[o];
    }
    vs[j] = vp * (1.0f / (float)Nn);
    ms[j] = mp * (1.0f / (float)Nn);
    __syncthreads();
    float s = brel2[j];
    for (int c = 0; c < Hh; ++c)
        s += vs[c] * Wrel2[c * Hh + j] + ms[c] * Wroot2[c * Hh + j];
    gs[j] = s;
    __syncthreads();
    float t = b1[j];
    for (int k = 0; k < Hh; ++k) t += gs[k] * W1[k * Hh + j];
    g2[j] = fmaxf(t, 0.f);
    __syncthreads();
    if (j < OUTD) {
        float s2 = bout[j];
        for (int k = 0; k < Hh; ++k) s2 += g2[k] * Wout[k * OUTD + j];
        out[b * OUTD + j] = s2;
    }
}

extern "C" void kernel_launch(void* const* d_in, const int* in_sizes, int n_in,
                              void* d_out, int out_size, void* d_ws, size_t ws_size,
                              hipStream_t stream) {
    const float* x      = (const float*)d_in[0];
    const float* sigma  = (const float*)d_in[4];
    const float* Wg     = (const float*)d_in[5];
    const float* bg     = (const float*)d_in[6];
    const float* Wrel0  = (const float*)d_in[7];
    const float* Wroot0 = (const float*)d_in[8];
    const float* brel0  = (const float*)d_in[9];
    const float* Wrel1  = (const float*)d_in[10];
    const float* Wroot1 = (const float*)d_in[11];
    const float* brel1  = (const float*)d_in[12];
    const float* Wrel2  = (const float*)d_in[13];
    const float* Wroot2 = (const float*)d_in[14];
    const float* brel2  = (const float*)d_in[15];
    const float* W1     = (const float*)d_in[16];
    const float* b1     = (const float*)d_in[17];
    const float* Wout   = (const float*)d_in[18];
    const float* bout   = (const float*)d_in[19];
    float* out = (float*)d_out;

    // Workspace layout (bytes)
    char* ws = (char*)d_ws;
    unsigned short* h0b  = (unsigned short*)(ws + 16777216);
    unsigned short* h0T  = (unsigned short*)(ws + 25165824);
    float*          sq   = (float*)(ws + 33554432);
    unsigned short* Aadj = (unsigned short*)(ws + 33685504);
    unsigned short* h1b  = (unsigned short*)(ws + 84017152);
    unsigned short* h1T  = (unsigned short*)(ws + 100794368);
    unsigned short* WrelT0  = (unsigned short*)(ws + 167903232);
    unsigned short* WrootT0 = (unsigned short*)(ws + 167968768);
    unsigned short* WrelT1  = (unsigned short*)(ws + 168034304);
    unsigned short* WrootT1 = (unsigned short*)(ws + 168165376);
    float*          w     = (float*)(ws + 168558592);
    float*          vpart = (float*)(ws + 168689664);
    float*          mpart = (float*)(ws + 169213952);

    // prep (weights + w zero) and h0 in one dispatch
    prep_h0<<<1152, 256, 0, stream>>>(x, Wg, bg, Wrel0, Wroot0, Wrel1, Wroot1,
                                      WrelT0, WrootT0, WrelT1, WrootT1,
                                      w, h0b, h0T, sq);

    // A = exp(-dist/(2 sigma^2)), zero diag; symmetric: 10 tiles/graph
    gram_A_sym<<<dim3(10 * Bsz, 1, 1), 512, 0, stream>>>(h0b, sq, sigma, Aadj, w);

    // ---- layer 0: fused A@h + dense (swizzled agg tile) ----
    fused_l0<<<dim3(4 * Bsz, 1, 1), 512, 0, stream>>>(
        h0T, Aadj, h0b, WrelT0, WrootT0, brel0, h1b, h1T);

    // ---- layer 1 + dense + layer-2-collapse pooling (swizzled agg tile) ----
    fused_l1<<<dim3(4 * Bsz, 1, 1), 512, 0, stream>>>(
        h1T, Aadj, h1b, WrelT1, WrootT1, brel1, w, vpart, mpart);

    // head
    head_kernel<<<Bsz, 256, 0, stream>>>(vpart, mpart, Wrel2, Wroot2, brel2,
                                         W1, b1, Wout, bout, out);
}

// Round 7
// 205.982 us; speedup vs baseline: 3.2821x; 1.0081x over previous
//
#include <hip/hip_runtime.h>
#include <math.h>

// Problem constants
#define Bsz 64
#define Nn 512
#define Ff 128
#define Hh 256
#define OUTD 6

typedef __bf16 bf16x8 __attribute__((ext_vector_type(8)));
typedef float f32x4 __attribute__((ext_vector_type(4)));
typedef unsigned short ushort4v __attribute__((ext_vector_type(4)));

__device__ __forceinline__ unsigned short f2bf(float f) {
    unsigned u = __float_as_uint(f);
    u += 0x7FFFu + ((u >> 16) & 1u);        // RNE
    return (unsigned short)(u >> 16);
}
__device__ __forceinline__ float bf2f(unsigned short s) {
    return __uint_as_float(((unsigned)s) << 16);
}

// XOR swizzle of the 16B k-chunk within a 64B LDS row
#define SWZ(r) (((r) ^ ((r) >> 2)) & 3)

// async 16B global->LDS (DMA; LDS dest = wave-uniform base + lane*16)
__device__ __forceinline__ void async_ld16(const unsigned short* g, unsigned short* l) {
    __builtin_amdgcn_global_load_lds(
        (const __attribute__((address_space(1))) void*)g,
        (__attribute__((address_space(3))) void*)l,
        16, 0, 0);
}

// counted vmcnt wait
__device__ __forceinline__ void wait_vm(int n) {
    switch (n) {
        case 0: asm volatile("s_waitcnt vmcnt(0)" ::: "memory"); break;
        case 1: asm volatile("s_waitcnt vmcnt(1)" ::: "memory"); break;
        case 2: asm volatile("s_waitcnt vmcnt(2)" ::: "memory"); break;
        case 3: asm volatile("s_waitcnt vmcnt(3)" ::: "memory"); break;
        case 4: asm volatile("s_waitcnt vmcnt(4)" ::: "memory"); break;
        case 5: asm volatile("s_waitcnt vmcnt(5)" ::: "memory"); break;
        default: asm volatile("s_waitcnt vmcnt(6)" ::: "memory"); break;
    }
}
__device__ __forceinline__ void pipe_barrier(int n) {
    wait_vm(n);
    __builtin_amdgcn_s_barrier();
    __builtin_amdgcn_sched_barrier(0);
}
__device__ __forceinline__ void drain_barrier() { pipe_barrier(0); }

#define LDH 40           // padded LDS row stride (bf16) for the h0 kernel
#define TSZ (128 * 32)   // 128 rows x 32 bf16 (8 KB)
#define ATS (256 * 32)   // 256 rows x 32 bf16 (16 KB)

// tiled swizzled LDS tile index: [kt][row][32] with 16B-chunk XOR swizzle
__device__ __forceinline__ int tsw_idx(int kt, int nl, int fo) {
    return kt * 4096 + nl * 32 + ((((fo >> 3) & 3) ^ SWZ(nl)) << 3) + (fo & 7);
}

// ---------------- FUSED gram + layer 0 ------------------------------------------
// One block per 128-node tile (4/graph, 256 blocks). Per 128-node k-chunk:
// Gram MFMA (h0c x h0r, K=128) + exp -> A-chunk in LDS (also written to global
// for fused_l1, row sums -> w). Stage 1 consumes the A-chunk from LDS as its
// B-operand (no A global read at all). Stage 2 = dense as before.
__global__ __launch_bounds__(512) void fused_l0_gram(
    const unsigned short* __restrict__ h0b,   // [node][128]
    const unsigned short* __restrict__ h0T,   // [graph][128][512]
    const unsigned short* __restrict__ WrelT0,  // [256][128]
    const unsigned short* __restrict__ WrootT0, // [256][128]
    const float* __restrict__ brel0,
    const float* __restrict__ sqv, const float* __restrict__ sigma,
    unsigned short* __restrict__ Aadj,  // [graph][512][512] (written here)
    float* __restrict__ w,              // [graph][512] row sums (written here)
    unsigned short* __restrict__ h1b,   // [node][256]
    unsigned short* __restrict__ h1T)   // [graph][256][512]
{
    int id = blockIdx.x;
    int b = id & 63;               // graph (XCD locality)
    int nt = id >> 6;              // node tile 0..3
    int n0g = nt * 128;
    long nodeBase = (long)b * Nn + n0g;

    const unsigned short* HT = h0T + (long)b * Ff * Nn;
    const float* SQ = sqv + (long)b * Nn;
    unsigned short* Ab = Aadj + (long)b * Nn * Nn;

    // SMEM union (123392 B total):
    // stage1: H0R@0(32K) H0C@32K(32K) ACH@64K(32K) SAh@96K(3x8K=24K) rsum@120.5K
    // stage2: AGK@0(32K) SA2@32K(48K) SB2@80K(24K)   (SAh/rsum dead by then)
    __shared__ __align__(16) unsigned char SMEM[123392];
    unsigned short* H0R = (unsigned short*)(SMEM);            // [4][128][32]
    unsigned short* H0C = (unsigned short*)(SMEM + 32768);    // [4][128][32]
    unsigned short* ACH = (unsigned short*)(SMEM + 65536);    // [4][128][32]
    unsigned short* SAh = (unsigned short*)(SMEM + 98304);    // 3 x [128][32]
    float* rsum = (float*)(SMEM + 122880);                    // [128]
    unsigned short* AGK = (unsigned short*)(SMEM);            // [4][128][32]
    unsigned short* SA2 = (unsigned short*)(SMEM + 32768);    // 3 x ATS
    unsigned short* SB2 = (unsigned short*)(SMEM + 81920);    // 3 x TSZ

    int tid = threadIdx.x;
    int lane = tid & 63;
    int wave = tid >> 6;
    int quad = lane >> 4, l16 = lane & 15;
    int sr = lane >> 2, sc = lane & 3;

    float sg = sigma[0];
    float inv2s2 = 1.0f / (2.0f * sg * sg);

    // staging lambdas
    auto issueH0R = [&]() {     // block's own 128 rows' feats -> [ks][node][32]
        int r = wave * 16 + sr;
        int c = sc ^ SWZ(r);
        #pragma unroll
        for (int kt = 0; kt < 4; ++kt)
            async_ld16(h0b + (nodeBase + r) * Ff + kt * 32 + c * 8,
                       H0R + kt * 4096 + (wave * 16) * 32);
    };
    auto issueH0C = [&](int kc) {   // chunk k-nodes' feats
        const unsigned short* src = h0b + ((long)b * Nn + kc * 128) * Ff;
        int r = wave * 16 + sr;
        int c = sc ^ SWZ(r);
        #pragma unroll
        for (int kt = 0; kt < 4; ++kt)
            async_ld16(src + (long)r * Ff + kt * 32 + c * 8,
                       H0C + kt * 4096 + (wave * 16) * 32);
    };
    auto issueHT = [&](int g) {     // h0T feat rows x 32 k-nodes
        int r = wave * 16 + sr;
        int c = sc ^ SWZ(r);
        async_ld16(HT + (long)r * Nn + g * 32 + c * 8,
                   SAh + (g % 3) * 4096 + (wave * 16) * 32);
    };

    // stage1 accumulators (M=128 feats x N=128 nodes)
    int wmS = (wave >> 1) * 32, wnS = (wave & 1) * 64;
    f32x4 accS1[2][4] = {};
    // Gram wave tile (M=128 k-rows x N=128 out-node cols)
    int wmG = (wave >> 1) * 32, wnG = (wave & 1) * 64;

    if (tid < 128) rsum[tid] = 0.f;
    issueH0R();
    issueH0C(0);
    issueHT(0);

    for (int kc = 0; kc < 4; ++kc) {
        drain_barrier();   // H0C(kc), hT(kc*4) landed (+H0R at kc=0); prev agg done

        // ---- Gram chunk: C[k][n] = h0[kc*128+k] . h0[n0g+n], K=128 feats ----
        f32x4 gr[2][4] = {};
        #pragma unroll
        for (int ks = 0; ks < 4; ++ks) {
            bf16x8 af[2], bfr[4];
            #pragma unroll
            for (int i = 0; i < 2; ++i) {
                int r = wmG + i * 16 + l16;
                af[i] = *(const bf16x8*)&H0C[ks * 4096 + r * 32 + (quad ^ SWZ(r)) * 8];
            }
            #pragma unroll
            for (int j = 0; j < 4; ++j) {
                int r = wnG + j * 16 + l16;
                bfr[j] = *(const bf16x8*)&H0R[ks * 4096 + r * 32 + (quad ^ SWZ(r)) * 8];
            }
            #pragma unroll
            for (int i = 0; i < 2; ++i)
                #pragma unroll
                for (int j = 0; j < 4; ++j)
                    gr[i][j] = __builtin_amdgcn_mfma_f32_16x16x32_bf16(
                        af[i], bfr[j], gr[i][j], 0, 0, 0);
        }

        // ---- exp epilogue: ACH (swizzled LDS) + global A write + w partials ----
        {
            float ws0 = 0.f, ws1 = 0.f, ws2 = 0.f, ws3 = 0.f;
            #pragma unroll
            for (int i = 0; i < 2; ++i) {
                int krow = wmG + i * 16 + quad * 4;
                int ktl = krow >> 5, fol = krow & 31;
                #pragma unroll
                for (int j = 0; j < 4; ++j) {
                    int n = wnG + j * 16 + l16;
                    int nglob = n0g + n;
                    float sqn = SQ[nglob];
                    f32x4 v = gr[i][j];
                    ushort4v pk;
                    float asum = 0.f;
                    #pragma unroll
                    for (int r4 = 0; r4 < 4; ++r4) {
                        int kglob = kc * 128 + krow + r4;
                        float d = fmaxf(sqn + SQ[kglob] - 2.0f * v[r4], 0.0f);
                        unsigned short a = (nglob == kglob) ? (unsigned short)0
                                                            : f2bf(__expf(-d * inv2s2));
                        pk[r4] = a;
                        asum += bf2f(a);
                    }
                    *(ushort4v*)&ACH[ktl * 4096 + n * 32 +
                                     ((((fol >> 3) ^ SWZ(n)) << 3) + (fol & 7))] = pk;
                    *(ushort4v*)&Ab[(long)nglob * Nn + kc * 128 + krow] = pk;
                    if (j == 0) ws0 += asum;
                    else if (j == 1) ws1 += asum;
                    else if (j == 2) ws2 += asum;
                    else ws3 += asum;
                }
            }
            #pragma unroll
            for (int j = 0; j < 4; ++j) {
                float cs = (j == 0) ? ws0 : (j == 1) ? ws1 : (j == 2) ? ws2 : ws3;
                cs += __shfl_xor(cs, 16);
                cs += __shfl_xor(cs, 32);
                if (lane < 16)
                    atomicAdd(&rsum[wnG + j * 16 + l16], cs);
            }
        }
        __syncthreads();   // ACH complete before agg reads

        // ---- agg: 4 k-slices of this chunk (B from ACH, A from h0T staging) ----
        for (int t = 0; t < 4; ++t) {
            int g = kc * 4 + t;
            if (t < 3) issueHT(g + 1);
            else if (kc < 3) { issueH0C(kc + 1); issueHT(g + 1); }
            pipe_barrier(t < 3 ? 1 : (kc < 3 ? 5 : 0));
            const unsigned short* Abf = SAh + (g % 3) * 4096;
            bf16x8 af[2], bfr[4];
            #pragma unroll
            for (int i = 0; i < 2; ++i) {
                int r = wmS + i * 16 + l16;
                af[i] = *(const bf16x8*)&Abf[r * 32 + (quad ^ SWZ(r)) * 8];
            }
            #pragma unroll
            for (int j = 0; j < 4; ++j) {
                int nl = wnS + j * 16 + l16;
                bfr[j] = *(const bf16x8*)&ACH[tsw_idx(t, nl, quad * 8)];
            }
            #pragma unroll
            for (int i = 0; i < 2; ++i)
                #pragma unroll
                for (int j = 0; j < 4; ++j)
                    accS1[i][j] = __builtin_amdgcn_mfma_f32_16x16x32_bf16(
                        af[i], bfr[j], accS1[i][j], 0, 0, 0);
        }
    }

    // ---- AGK epilogue (aliases H0R region; all H0R reads long done) ----
    #pragma unroll
    for (int i = 0; i < 2; ++i) {
        int f = wmS + i * 16 + quad * 4;
        int kt = f >> 5, fo = f & 31;
        #pragma unroll
        for (int j = 0; j < 4; ++j) {
            int nl = wnS + j * 16 + l16;
            f32x4 v = accS1[i][j];
            ushort4v p;
            p[0] = f2bf(v[0]); p[1] = f2bf(v[1]);
            p[2] = f2bf(v[2]); p[3] = f2bf(v[3]);
            *(ushort4v*)&AGK[tsw_idx(kt, nl, fo)] = p;
        }
    }
    __syncthreads();
    if (tid < 128) w[(long)b * Nn + n0g + tid] = rsum[tid];   // block-private rows

    // ---------- stage 2: dense, M=256 outfeats x N=128 nodes, wave tile 64x64 ----------
    {
        int wm = (wave >> 1) * 64, wn = (wave & 1) * 64;
        f32x4 acc[4][4] = {};
        auto issue2 = [&](int g) {
            const unsigned short* Wp = (g < 4) ? WrelT0 : WrootT0;
            int kk = (g & 3) << 5;
            unsigned short* Ad = SA2 + (g % 3) * ATS;
            int r = wave * 16 + sr;
            int c = sc ^ SWZ(r);
            async_ld16(Wp + (long)r * Ff + kk + c * 8, Ad + (wave * 16) * 32);
            int r2 = 128 + r;
            int c2 = sc ^ SWZ(r2);
            async_ld16(Wp + (long)r2 * Ff + kk + c2 * 8, Ad + (128 + wave * 16) * 32);
            if (g >= 4) {
                unsigned short* Bd = SB2 + (g % 3) * TSZ;
                async_ld16(h0b + (nodeBase + r) * Ff + kk + c * 8,
                           Bd + (wave * 16) * 32);
            }
        };
        issue2(0); issue2(1);
        for (int g = 0; g < 8; ++g) {
            int nx = g + 1;
            pipe_barrier(nx >= 8 ? 0 : (nx < 4 ? 2 : 3));
            if (g + 2 < 8) issue2(g + 2);
            const unsigned short* Abf = SA2 + (g % 3) * ATS;
            bf16x8 af[4], bfr[4];
            #pragma unroll
            for (int i = 0; i < 4; ++i) {
                int r = wm + i * 16 + l16;
                af[i] = *(const bf16x8*)&Abf[r * 32 + (quad ^ SWZ(r)) * 8];
            }
            if (g < 4) {
                #pragma unroll
                for (int j = 0; j < 4; ++j) {
                    int nl = wn + j * 16 + l16;
                    bfr[j] = *(const bf16x8*)&AGK[tsw_idx(g, nl, quad * 8)];
                }
            } else {
                const unsigned short* Bb = SB2 + (g % 3) * TSZ;
                #pragma unroll
                for (int j = 0; j < 4; ++j) {
                    int r = wn + j * 16 + l16;
                    bfr[j] = *(const bf16x8*)&Bb[r * 32 + (quad ^ SWZ(r)) * 8];
                }
            }
            #pragma unroll
            for (int i = 0; i < 4; ++i)
                #pragma unroll
                for (int j = 0; j < 4; ++j)
                    acc[i][j] = __builtin_amdgcn_mfma_f32_16x16x32_bf16(
                        af[i], bfr[j], acc[i][j], 0, 0, 0);
        }
        #pragma unroll
        for (int i = 0; i < 4; ++i) {
            int of = wm + i * 16 + quad * 4;
            float b0 = brel0[of + 0], b1 = brel0[of + 1];
            float b2 = brel0[of + 2], b3 = brel0[of + 3];
            #pragma unroll
            for (int j = 0; j < 4; ++j) {
                int nl = wn + j * 16 + l16;
                f32x4 v = acc[i][j];
                float o0 = fmaxf(v[0] + b0, 0.f), o1 = fmaxf(v[1] + b1, 0.f);
                float o2 = fmaxf(v[2] + b2, 0.f), o3 = fmaxf(v[3] + b3, 0.f);
                ushort4v p;
                p[0] = f2bf(o0); p[1] = f2bf(o1); p[2] = f2bf(o2); p[3] = f2bf(o3);
                *(ushort4v*)&h1b[(nodeBase + nl) * Hh + of] = p;
                long base = ((long)b * Hh) * 512 + n0g + nl;
                h1T[base + (long)(of + 0) * 512] = p[0];
                h1T[base + (long)(of + 1) * 512] = p[1];
                h1T[base + (long)(of + 2) * 512] = p[2];
                h1T[base + (long)(of + 3) * 512] = p[3];
            }
        }
    }
}

// ---------------- FUSED layer 1 + layer-2-collapse pooling (unchanged) -----------
__global__ __launch_bounds__(512) void fused_l1(
    const unsigned short* __restrict__ h1T,
    const unsigned short* __restrict__ Arows,
    const unsigned short* __restrict__ h1b,
    const unsigned short* __restrict__ WrelT1,
    const unsigned short* __restrict__ WrootT1,
    const float* __restrict__ brel1,
    const float* __restrict__ w,
    float* __restrict__ vpart, float* __restrict__ mpart)
{
    constexpr int BTS = 128 * 32;

    int id = blockIdx.x;
    int b = id & 63;
    int nt = id >> 6;
    int n0g = nt * 128;
    long nodeBase = (long)b * Nn + n0g;

    const unsigned short* HT = h1T + (long)b * Hh * Nn;
    const unsigned short* AR = Arows + (long)b * Nn * Nn;

    __shared__ unsigned short SA[3 * ATS];
    __shared__ unsigned short SB[3 * BTS];
    __shared__ unsigned short AGK[8 * 128 * 32];

    int tid = threadIdx.x;
    int lane = tid & 63;
    int wave = tid >> 6;
    int quad = lane >> 4, l16 = lane & 15;
    int wm = (wave >> 1) * 64;
    int wn = (wave & 1) * 64;
    int sr = lane >> 2, sc = lane & 3;

    {
        f32x4 acc[4][4] = {};
        auto issue = [&](int g) {
            int kk = g << 5;
            unsigned short* Ad = SA + (g % 3) * ATS;
            int r = wave * 16 + sr;
            int c = sc ^ SWZ(r);
            async_ld16(HT + (long)r * Nn + kk + c * 8, Ad + (wave * 16) * 32);
            int r2 = 128 + r;
            int c2 = sc ^ SWZ(r2);
            async_ld16(HT + (long)r2 * Nn + kk + c2 * 8, Ad + (128 + wave * 16) * 32);
            unsigned short* Bd = SB + (g % 3) * BTS;
            async_ld16(AR + (long)(n0g + r) * Nn + kk + c * 8, Bd + (wave * 16) * 32);
        };
        issue(0); issue(1);
        for (int g = 0; g < 16; ++g) {
            pipe_barrier(g + 1 < 16 ? 3 : 0);
            if (g + 2 < 16) issue(g + 2);
            const unsigned short* Ab = SA + (g % 3) * ATS;
            const unsigned short* Bb = SB + (g % 3) * BTS;
            bf16x8 af[4], bfr[4];
            #pragma unroll
            for (int i = 0; i < 4; ++i) {
                int r = wm + i * 16 + l16;
                af[i] = *(const bf16x8*)&Ab[r * 32 + (quad ^ SWZ(r)) * 8];
            }
            #pragma unroll
            for (int j = 0; j < 4; ++j) {
                int r = wn + j * 16 + l16;
                bfr[j] = *(const bf16x8*)&Bb[r * 32 + (quad ^ SWZ(r)) * 8];
            }
            #pragma unroll
            for (int i = 0; i < 4; ++i)
                #pragma unroll
                for (int j = 0; j < 4; ++j)
                    acc[i][j] = __builtin_amdgcn_mfma_f32_16x16x32_bf16(
                        af[i], bfr[j], acc[i][j], 0, 0, 0);
        }
        #pragma unroll
        for (int i = 0; i < 4; ++i) {
            int f = wm + i * 16 + quad * 4;
            int kt = f >> 5, fo = f & 31;
            #pragma unroll
            for (int j = 0; j < 4; ++j) {
                int nl = wn + j * 16 + l16;
                f32x4 v = acc[i][j];
                ushort4v p;
                p[0] = f2bf(v[0]); p[1] = f2bf(v[1]);
                p[2] = f2bf(v[2]); p[3] = f2bf(v[3]);
                *(ushort4v*)&AGK[tsw_idx(kt, nl, fo)] = p;
            }
        }
    }
    __syncthreads();

    f32x4 acc[4][4] = {};
    auto issue2 = [&](int g) {
        const unsigned short* Wp = (g < 8) ? WrelT1 : WrootT1;
        int kk = (g & 7) << 5;
        unsigned short* Ad = SA + (g % 3) * ATS;
        int r = wave * 16 + sr;
        int c = sc ^ SWZ(r);
        async_ld16(Wp + (long)r * Hh + kk + c * 8, Ad + (wave * 16) * 32);
        int r2 = 128 + r;
        int c2 = sc ^ SWZ(r2);
        async_ld16(Wp + (long)r2 * Hh + kk + c2 * 8, Ad + (128 + wave * 16) * 32);
        if (g >= 8) {
            unsigned short* Bd = SB + (g % 3) * BTS;
            async_ld16(h1b + (nodeBase + r) * Hh + kk + c * 8, Bd + (wave * 16) * 32);
        }
    };
    issue2(0); issue2(1);
    for (int g = 0; g < 16; ++g) {
        int nx = g + 1;
        pipe_barrier(nx >= 16 ? 0 : (nx < 8 ? 2 : 3));
        if (g + 2 < 16) issue2(g + 2);
        const unsigned short* Ab = SA + (g % 3) * ATS;
        bf16x8 af[4], bfr[4];
        #pragma unroll
        for (int i = 0; i < 4; ++i) {
            int r = wm + i * 16 + l16;
            af[i] = *(const bf16x8*)&Ab[r * 32 + (quad ^ SWZ(r)) * 8];
        }
        if (g < 8) {
            #pragma unroll
            for (int j = 0; j < 4; ++j) {
                int nl = wn + j * 16 + l16;
                bfr[j] = *(const bf16x8*)&AGK[tsw_idx(g, nl, quad * 8)];
            }
        } else {
            const unsigned short* Bb = SB + (g % 3) * BTS;
            #pragma unroll
            for (int j = 0; j < 4; ++j) {
                int r = wn + j * 16 + l16;
                bfr[j] = *(const bf16x8*)&Bb[r * 32 + (quad ^ SWZ(r)) * 8];
            }
        }
        #pragma unroll
        for (int i = 0; i < 4; ++i)
            #pragma unroll
            for (int j = 0; j < 4; ++j)
                acc[i][j] = __builtin_amdgcn_mfma_f32_16x16x32_bf16(
                    af[i], bfr[j], acc[i][j], 0, 0, 0);
    }

    #pragma unroll
    for (int i = 0; i < 4; ++i) {
        int lf = wm + i * 16 + quad * 4;
        float b0 = brel1[lf + 0], b1 = brel1[lf + 1];
        float b2 = brel1[lf + 2], b3 = brel1[lf + 3];
        float vp0 = 0.f, vp1 = 0.f, vp2 = 0.f, vp3 = 0.f;
        float mp0 = 0.f, mp1 = 0.f, mp2 = 0.f, mp3 = 0.f;
        #pragma unroll
        for (int j = 0; j < 4; ++j) {
            long node = nodeBase + wn + j * 16 + l16;
            f32x4 v = acc[i][j];
            float o0 = fmaxf(v[0] + b0, 0.f), o1 = fmaxf(v[1] + b1, 0.f);
            float o2 = fmaxf(v[2] + b2, 0.f), o3 = fmaxf(v[3] + b3, 0.f);
            float h0v = bf2f(f2bf(o0)), h1v = bf2f(f2bf(o1));
            float h2v = bf2f(f2bf(o2)), h3v = bf2f(f2bf(o3));
            float wv = w[node];
            vp0 += wv * h0v; vp1 += wv * h1v; vp2 += wv * h2v; vp3 += wv * h3v;
            mp0 += h0v; mp1 += h1v; mp2 += h2v; mp3 += h3v;
        }
        #pragma unroll
        for (int m = 1; m < 16; m <<= 1) {
            vp0 += __shfl_xor(vp0, m); vp1 += __shfl_xor(vp1, m);
            vp2 += __shfl_xor(vp2, m); vp3 += __shfl_xor(vp3, m);
            mp0 += __shfl_xor(mp0, m); mp1 += __shfl_xor(mp1, m);
            mp2 += __shfl_xor(mp2, m); mp3 += __shfl_xor(mp3, m);
        }
        if (l16 == 0) {
            long o = ((long)(b * 8 + nt * 2 + (wave & 1))) * Hh + lf;
            float4 vv = {vp0, vp1, vp2, vp3};
            float4 mm = {mp0, mp1, mp2, mp3};
            *(float4*)&vpart[o] = vv;
            *(float4*)&mpart[o] = mm;
        }
    }
}

// ---------------- prep: weight convert/transpose + w zero + h0 MFMA ------------
__global__ __launch_bounds__(256) void prep_h0(
    const float* __restrict__ x, const float* __restrict__ Wg,
    const float* __restrict__ bg,
    const float* __restrict__ Wrel0, const float* __restrict__ Wroot0,
    const float* __restrict__ Wrel1, const float* __restrict__ Wroot1,
    unsigned short* __restrict__ T0, unsigned short* __restrict__ T1,
    unsigned short* __restrict__ T2, unsigned short* __restrict__ T3,
    float* __restrict__ w,
    unsigned short* __restrict__ h0b, unsigned short* __restrict__ h0T,
    float* __restrict__ sqv)
{
    if (blockIdx.x < 896) {
        int idx = blockIdx.x * 256 + threadIdx.x;
        if (idx >= 196608) { w[idx - 196608] = 0.f; return; }
        const float* src; unsigned short* dst; int kin; int e;
        if      (idx <  32768) { src = Wrel0;  dst = T0; kin = 128; e = idx; }
        else if (idx <  65536) { src = Wroot0; dst = T1; kin = 128; e = idx - 32768; }
        else if (idx < 131072) { src = Wrel1;  dst = T2; kin = 256; e = idx - 65536; }
        else                   { src = Wroot1; dst = T3; kin = 256; e = idx - 131072; }
        int o = (kin == 128) ? (e >> 7) : (e >> 8);
        int i = e & (kin - 1);
        dst[e] = f2bf(src[(long)i * 256 + o]);
        return;
    }

    __shared__ unsigned short As[128 * LDH];
    __shared__ unsigned short Bs[128 * LDH];
    __shared__ float rsq[128];

    int tid = threadIdx.x;
    int lane = tid & 63;
    int wave = tid >> 6;
    int quad = lane >> 4, l16 = lane & 15;
    int wm = (wave >> 1) * 64, wn = (wave & 1) * 64;
    int m0 = (blockIdx.x - 896) * 128;

    f32x4 acc[4][4] = {};

    for (int k0 = 0; k0 < Ff; k0 += 32) {
        __syncthreads();
        #pragma unroll
        for (int l = 0; l < 2; ++l) {
            int idx = tid + l * 256;
            int r = idx >> 2, ch = idx & 3;
            const float* px = x + (long)(m0 + r) * Ff + k0 + ch * 8;
            float4 xa = *(const float4*)px;
            float4 xb = *(const float4*)(px + 4);
            ushort4v pa, pb;
            pa[0] = f2bf(xa.x); pa[1] = f2bf(xa.y); pa[2] = f2bf(xa.z); pa[3] = f2bf(xa.w);
            pb[0] = f2bf(xb.x); pb[1] = f2bf(xb.y); pb[2] = f2bf(xb.z); pb[3] = f2bf(xb.w);
            *(ushort4v*)&As[r * LDH + ch * 8] = pa;
            *(ushort4v*)&As[r * LDH + ch * 8 + 4] = pb;
            int kk = k0 + ch * 8;
            ushort4v qa, qb;
            #pragma unroll
            for (int u = 0; u < 4; ++u) qa[u] = f2bf(Wg[(long)(kk + u) * 128 + r]);
            #pragma unroll
            for (int u = 0; u < 4; ++u) qb[u] = f2bf(Wg[(long)(kk + 4 + u) * 128 + r]);
            *(ushort4v*)&Bs[r * LDH + ch * 8] = qa;
            *(ushort4v*)&Bs[r * LDH + ch * 8 + 4] = qb;
        }
        __syncthreads();
        bf16x8 af[4], bfr[4];
        #pragma unroll
        for (int i = 0; i < 4; ++i)
            af[i] = *(const bf16x8*)&As[(wm + i * 16 + l16) * LDH + quad * 8];
        #pragma unroll
        for (int j = 0; j < 4; ++j)
            bfr[j] = *(const bf16x8*)&Bs[(wn + j * 16 + l16) * LDH + quad * 8];
        #pragma unroll
        for (int i = 0; i < 4; ++i)
            #pragma unroll
            for (int j = 0; j < 4; ++j)
                acc[i][j] = __builtin_amdgcn_mfma_f32_16x16x32_bf16(
                    af[i], bfr[j], acc[i][j], 0, 0, 0);
    }

    if (tid < 128) rsq[tid] = 0.f;
    __syncthreads();

    #pragma unroll
    for (int i = 0; i < 4; ++i) {
        int lrow = wm + i * 16 + quad * 4;
        int mb = m0 + lrow;
        float rp0 = 0.f, rp1 = 0.f, rp2 = 0.f, rp3 = 0.f;
        #pragma unroll
        for (int j = 0; j < 4; ++j) {
            int n = wn + j * 16 + l16;
            f32x4 v = acc[i][j];
            float bv = bg[n];
            unsigned short s0 = f2bf(v[0] + bv), s1 = f2bf(v[1] + bv);
            unsigned short s2 = f2bf(v[2] + bv), s3 = f2bf(v[3] + bv);
            h0b[(long)(mb + 0) * Ff + n] = s0;
            h0b[(long)(mb + 1) * Ff + n] = s1;
            h0b[(long)(mb + 2) * Ff + n] = s2;
            h0b[(long)(mb + 3) * Ff + n] = s3;
            ushort4v p; p[0] = s0; p[1] = s1; p[2] = s2; p[3] = s3;
            long ti = ((long)(mb >> 9) * Ff + n) * 512 + (mb & 511);
            *(ushort4v*)&h0T[ti] = p;
            float f0 = bf2f(s0), f1 = bf2f(s1), f2 = bf2f(s2), f3 = bf2f(s3);
            rp0 += f0 * f0; rp1 += f1 * f1; rp2 += f2 * f2; rp3 += f3 * f3;
        }
        #pragma unroll
        for (int m = 1; m < 16; m <<= 1) {
            rp0 += __shfl_xor(rp0, m);
            rp1 += __shfl_xor(rp1, m);
            rp2 += __shfl_xor(rp2, m);
            rp3 += __shfl_xor(rp3, m);
        }
        if (l16 == 0) {
            atomicAdd(&rsq[lrow + 0], rp0);
            atomicAdd(&rsq[lrow + 1], rp1);
            atomicAdd(&rsq[lrow + 2], rp2);
            atomicAdd(&rsq[lrow + 3], rp3);
        }
    }
    __syncthreads();
    if (tid < 128) sqv[m0 + tid] = rsq[tid];
}

// ---------------- head: unchanged ----------------------------------------------
__global__ __launch_bounds__(256) void head_kernel(
    const float* __restrict__ vpart, const float* __restrict__ mpart,
    const float* __restrict__ Wrel2, const float* __restrict__ Wroot2,
    const float* __restrict__ brel2,
    const float* __restrict__ W1, const float* __restrict__ b1,
    const float* __restrict__ Wout, const float* __restrict__ bout,
    float* __restrict__ out)
{
    int b = blockIdx.x;
    int j = threadIdx.x;
    __shared__ float vs[Hh], ms[Hh], gs[Hh], g2[Hh];
    float vp = 0.f, mp = 0.f;
    #pragma unroll
    for (int p = 0; p < 8; ++p) {
        long o = ((long)(b * 8 + p)) * Hh + j;
        vp += vpart[o];
        mp += mpart[o];
    }
    vs[j] = vp * (1.0f / (float)Nn);
    ms[j] = mp * (1.0f / (float)Nn);
    __syncthreads();
    float s = brel2[j];
    for (int c = 0; c < Hh; ++c)
        s += vs[c] * Wrel2[c * Hh + j] + ms[c] * Wroot2[c * Hh + j];
    gs[j] = s;
    __syncthreads();
    float t = b1[j];
    for (int k = 0; k < Hh; ++k) t += gs[k] * W1[k * Hh + j];
    g2[j] = fmaxf(t, 0.f);
    __syncthreads();
    if (j < OUTD) {
        float s2 = bout[j];
        for (int k = 0; k < Hh; ++k) s2 += g2[k] * Wout[k * OUTD + j];
        out[b * OUTD + j] = s2;
    }
}

extern "C" void kernel_launch(void* const* d_in, const int* in_sizes, int n_in,
                              void* d_out, int out_size, void* d_ws, size_t ws_size,
                              hipStream_t stream) {
    const float* x      = (const float*)d_in[0];
    const float* sigma  = (const float*)d_in[4];
    const float* Wg     = (const float*)d_in[5];
    const float* bg     = (const float*)d_in[6];
    const float* Wrel0  = (const float*)d_in[7];
    const float* Wroot0 = (const float*)d_in[8];
    const float* brel0  = (const float*)d_in[9];
    const float* Wrel1  = (const float*)d_in[10];
    const float* Wroot1 = (const float*)d_in[11];
    const float* brel1  = (const float*)d_in[12];
    const float* Wrel2  = (const float*)d_in[13];
    const float* Wroot2 = (const float*)d_in[14];
    const float* brel2  = (const float*)d_in[15];
    const float* W1     = (const float*)d_in[16];
    const float* b1     = (const float*)d_in[17];
    const float* Wout   = (const float*)d_in[18];
    const float* bout   = (const float*)d_in[19];
    float* out = (float*)d_out;

    // Workspace layout (bytes)
    char* ws = (char*)d_ws;
    unsigned short* h0b  = (unsigned short*)(ws + 16777216);
    unsigned short* h0T  = (unsigned short*)(ws + 25165824);
    float*          sq   = (float*)(ws + 33554432);
    unsigned short* Aadj = (unsigned short*)(ws + 33685504);
    unsigned short* h1b  = (unsigned short*)(ws + 84017152);
    unsigned short* h1T  = (unsigned short*)(ws + 100794368);
    unsigned short* WrelT0  = (unsigned short*)(ws + 167903232);
    unsigned short* WrootT0 = (unsigned short*)(ws + 167968768);
    unsigned short* WrelT1  = (unsigned short*)(ws + 168034304);
    unsigned short* WrootT1 = (unsigned short*)(ws + 168165376);
    float*          w     = (float*)(ws + 168558592);
    float*          vpart = (float*)(ws + 168689664);
    float*          mpart = (float*)(ws + 169213952);

    // prep (weights + w zero) and h0 in one dispatch
    prep_h0<<<1152, 256, 0, stream>>>(x, Wg, bg, Wrel0, Wroot0, Wrel1, Wroot1,
                                      WrelT0, WrootT0, WrelT1, WrootT1,
                                      w, h0b, h0T, sq);

    // ---- fused gram + layer 0: A computed inline (LDS), written for l1; w too ----
    fused_l0_gram<<<dim3(4 * Bsz, 1, 1), 512, 0, stream>>>(
        h0b, h0T, WrelT0, WrootT0, brel0, sq, sigma, Aadj, w, h1b, h1T);

    // ---- layer 1 + dense + layer-2-collapse pooling ----
    fused_l1<<<dim3(4 * Bsz, 1, 1), 512, 0, stream>>>(
        h1T, Aadj, h1b, WrelT1, WrootT1, brel1, w, vpart, mpart);

    // head
    head_kernel<<<Bsz, 256, 0, stream>>>(vpart, mpart, Wrel2, Wroot2, brel2,
                                         W1, b1, Wout, bout, out);
}